// Round 1
// baseline (1744.166 us; speedup 1.0000x reference)
//
#include <hip/hip_runtime.h>
#include <hip/hip_bf16.h>

typedef __bf16 bf16x8 __attribute__((ext_vector_type(8)));
typedef float f32x4 __attribute__((ext_vector_type(4)));

#define NTOK 49
#define NH   6
#define HDIM 56
#define DIMC 192
#define SCALE 0.17677669529663687f

// workspace layout (bytes)
#define WS_QKVWT  0          // bf16 [1008][192]  (transposed qkv_w)
#define WS_PROJWT 387072     // bf16 [192][384]   (transposed proj_w, K padded to 384 w/ zeros)
#define WS_BIAS6  534528     // f32  [6][49][49]  (gathered rel bias)

// LDS layout (bytes). qs region is reused for (out+lepe) in P4/P5.
#define XS_OFF  0            // bf16 [64][192] swizzled
#define QS_OFF  24576        // bf16 [64][64]  swizzled (q, later out+lepe)
#define KS_OFF  32768        // bf16 [64][64]  swizzled
#define VT_OFF  40960        // bf16 [64][64]  swizzled (v transposed: [d][m'])
#define ATT_OFF 49152        // bf16 [64][64]  swizzled (P post-softmax)
#define SMEM_BYTES 57344

__device__ __forceinline__ unsigned swzaddr(unsigned base, int row, int colb, int strideb) {
  return base + (unsigned)((row * strideb + colb) ^ ((row & 7) << 4));
}

__device__ __forceinline__ unsigned short f2bu(float f) {
  __hip_bfloat16 h = __float2bfloat16(f);
  unsigned short u;
  __builtin_memcpy(&u, &h, 2);
  return u;
}

__global__ void prep_kernel(const float* __restrict__ qkv_w,
                            const float* __restrict__ proj_w,
                            const float* __restrict__ tbl,
                            const int* __restrict__ ridx,
                            unsigned char* __restrict__ ws) {
  __hip_bfloat16* qkvwt  = (__hip_bfloat16*)(ws + WS_QKVWT);
  __hip_bfloat16* projwt = (__hip_bfloat16*)(ws + WS_PROJWT);
  float* bias6 = (float*)(ws + WS_BIAS6);
  int idx = blockIdx.x * 256 + threadIdx.x;
  const int n1 = 1008 * 192;
  const int n2 = 192 * 384;
  const int n3 = 6 * 49 * 49;
  if (idx < n1) {
    int c = idx / 192, k = idx - c * 192;
    qkvwt[idx] = __float2bfloat16(qkv_w[k * 1008 + c]);
  } else if (idx < n1 + n2) {
    int j = idx - n1;
    int c = j / 384, kk = j - c * 384;
    projwt[j] = __float2bfloat16(kk < 336 ? proj_w[kk * 192 + c] : 0.0f);
  } else if (idx < n1 + n2 + n3) {
    int j = idx - n1 - n2;
    int h = j / 2401, mn = j - h * 2401;
    bias6[j] = tbl[ridx[mn] * 6 + h];
  }
}

__global__ __launch_bounds__(256, 2) void winattn_kernel(
    const float* __restrict__ x, const float* __restrict__ mask,
    const float* __restrict__ qkv_b, const float* __restrict__ lepe_w,
    const float* __restrict__ lepe_b, const float* __restrict__ proj_b,
    const unsigned char* __restrict__ ws, float* __restrict__ out) {
  __shared__ uint4 smem4[SMEM_BYTES / 16];
  unsigned char* sm = (unsigned char*)smem4;
  const __hip_bfloat16* qkvwt  = (const __hip_bfloat16*)(ws + WS_QKVWT);
  const __hip_bfloat16* projwt = (const __hip_bfloat16*)(ws + WS_PROJWT);
  const float* bias6 = (const float*)(ws + WS_BIAS6);

  const int tid = threadIdx.x;
  const int lane = tid & 63, wv = tid >> 6;
  const int l15 = lane & 15, l4 = lane >> 4;
  const int blk = blockIdx.x;
  const int wdx = blk & 63;

  // zero xs pad rows (49..63) + all of qs/ks/vt/att: bytes [18816, 57344)
  {
    uint4 z = {0u, 0u, 0u, 0u};
    for (int i = tid; i < 2408; i += 256) ((uint4*)(sm + 18816))[i] = z;
  }

  // stage x -> xs (bf16, swizzled). 49 rows * 24 chunks of 16B.
  const float* xg = x + (size_t)blk * (NTOK * DIMC);
  for (int cid = tid; cid < NTOK * 24; cid += 256) {
    int row = cid / 24, c8 = cid - row * 24;
    const float4* src = (const float4*)(xg + row * DIMC + c8 * 8);
    float4 a = src[0], b = src[1];
    union { unsigned short u[8]; uint4 q; } pk;
    pk.u[0] = f2bu(a.x); pk.u[1] = f2bu(a.y); pk.u[2] = f2bu(a.z); pk.u[3] = f2bu(a.w);
    pk.u[4] = f2bu(b.x); pk.u[5] = f2bu(b.y); pk.u[6] = f2bu(b.z); pk.u[7] = f2bu(b.w);
    *(uint4*)(sm + swzaddr(XS_OFF, row, c8 * 16, 384)) = pk.q;
  }
  __syncthreads();

  const int arow = wv * 16 + l15;

  // persistent proj accumulators (12 n-tiles of 16 cols = 192)
  f32x4 pacc[12];
#pragma unroll
  for (int nt = 0; nt < 12; ++nt) {
    float pb = proj_b[nt * 16 + l15];
    pacc[nt] = (f32x4){pb, pb, pb, pb};
  }

  // A-fragments of x (reused every head): rows arow, 6 k-tiles of 32
  bf16x8 afr[6];
#pragma unroll
  for (int kt = 0; kt < 6; ++kt)
    afr[kt] = *(const bf16x8*)(sm + swzaddr(XS_OFF, arow, (kt * 32 + l4 * 8) * 2, 384));

  for (int h = 0; h < NH; ++h) {
    // ---------------- P1: qkv = x @ W_h + b  (49 x 168) ----------------
#pragma unroll
    for (int nt = 0; nt < 11; ++nt) {
      int cl = nt * 16 + l15;               // 0..175 (>=168 discarded)
      int cg = h * 168 + cl; if (cg > 1007) cg = 1007;
      float bias = qkv_b[cg];
      f32x4 acc = (f32x4){bias, bias, bias, bias};
#pragma unroll
      for (int kt = 0; kt < 6; ++kt) {
        bf16x8 bf = *(const bf16x8*)(qkvwt + cg * DIMC + kt * 32 + l4 * 8);
        acc = __builtin_amdgcn_mfma_f32_16x16x32_bf16(afr[kt], bf, acc, 0, 0, 0);
      }
      if (cl < 168) {
#pragma unroll
        for (int r = 0; r < 4; ++r) {
          int m = wv * 16 + l4 * 4 + r;
          if (m < NTOK) {
            float vv = acc[r];
            if (cl < 56)
              *(__hip_bfloat16*)(sm + swzaddr(QS_OFF, m, cl * 2, 128)) = __float2bfloat16(vv);
            else if (cl < 112)
              *(__hip_bfloat16*)(sm + swzaddr(KS_OFF, m, (cl - 56) * 2, 128)) = __float2bfloat16(vv);
            else
              *(__hip_bfloat16*)(sm + swzaddr(VT_OFF, cl - 112, m * 2, 128)) = __float2bfloat16(vv);
          }
        }
      }
    }
    __syncthreads();

    // ---------------- P2: S = scale*(q k^T) + bias + mask; softmax ----------------
    bf16x8 qa[2];
#pragma unroll
    for (int kt = 0; kt < 2; ++kt)
      qa[kt] = *(const bf16x8*)(sm + swzaddr(QS_OFF, arow, (kt * 32 + l4 * 8) * 2, 128));
    f32x4 sv[4];
#pragma unroll
    for (int nt = 0; nt < 4; ++nt) {
      f32x4 acc = (f32x4){0.f, 0.f, 0.f, 0.f};
#pragma unroll
      for (int kt = 0; kt < 2; ++kt) {
        bf16x8 kb = *(const bf16x8*)(sm + swzaddr(KS_OFF, nt * 16 + l15, (kt * 32 + l4 * 8) * 2, 128));
        acc = __builtin_amdgcn_mfma_f32_16x16x32_bf16(qa[kt], kb, acc, 0, 0, 0);
      }
      sv[nt] = acc;
    }
#pragma unroll
    for (int nt = 0; nt < 4; ++nt) {
      int n = nt * 16 + l15;
#pragma unroll
      for (int r = 0; r < 4; ++r) {
        int m = wv * 16 + l4 * 4 + r;
        int mc = m < NTOK ? m : NTOK - 1;
        float vv;
        if (n < NTOK)
          vv = SCALE * sv[nt][r] + bias6[(h * NTOK + mc) * NTOK + n] + mask[(wdx * NTOK + mc) * NTOK + n];
        else
          vv = -1e30f;
        sv[nt][r] = vv;
      }
    }
#pragma unroll
    for (int r = 0; r < 4; ++r) {
      float mx = fmaxf(fmaxf(sv[0][r], sv[1][r]), fmaxf(sv[2][r], sv[3][r]));
      mx = fmaxf(mx, __shfl_xor(mx, 1));
      mx = fmaxf(mx, __shfl_xor(mx, 2));
      mx = fmaxf(mx, __shfl_xor(mx, 4));
      mx = fmaxf(mx, __shfl_xor(mx, 8));
      float p0 = expf(sv[0][r] - mx), p1 = expf(sv[1][r] - mx);
      float p2 = expf(sv[2][r] - mx), p3 = expf(sv[3][r] - mx);
      float sum = p0 + p1 + p2 + p3;
      sum += __shfl_xor(sum, 1);
      sum += __shfl_xor(sum, 2);
      sum += __shfl_xor(sum, 4);
      sum += __shfl_xor(sum, 8);
      float rinv = 1.0f / sum;
      sv[0][r] = p0 * rinv; sv[1][r] = p1 * rinv; sv[2][r] = p2 * rinv; sv[3][r] = p3 * rinv;
    }
#pragma unroll
    for (int nt = 0; nt < 4; ++nt) {
      int n = nt * 16 + l15;
#pragma unroll
      for (int r = 0; r < 4; ++r) {
        int m = wv * 16 + l4 * 4 + r;
        if (m < NTOK)
          *(__hip_bfloat16*)(sm + swzaddr(ATT_OFF, m, n * 2, 128)) = __float2bfloat16(sv[nt][r]);
      }
    }

    // ---------------- P3: O = P @ V  (49 x 56) ----------------
    bf16x8 pa[2];
#pragma unroll
    for (int kt = 0; kt < 2; ++kt)
      pa[kt] = *(const bf16x8*)(sm + swzaddr(ATT_OFF, arow, (kt * 32 + l4 * 8) * 2, 128));
    f32x4 ov[4];
#pragma unroll
    for (int nt = 0; nt < 4; ++nt) {
      f32x4 acc = (f32x4){0.f, 0.f, 0.f, 0.f};
#pragma unroll
      for (int kt = 0; kt < 2; ++kt) {
        bf16x8 vb = *(const bf16x8*)(sm + swzaddr(VT_OFF, nt * 16 + l15, (kt * 32 + l4 * 8) * 2, 128));
        acc = __builtin_amdgcn_mfma_f32_16x16x32_bf16(pa[kt], vb, acc, 0, 0, 0);
      }
      ov[nt] = acc;
    }

    // ---------------- P4: lepe (depthwise 3x3 on v) + store O+lepe into QS region ----------------
#pragma unroll
    for (int nt = 0; nt < 4; ++nt) {
      int d = nt * 16 + l15;
      if (d < HDIM) {
        const float* lw = lepe_w + (h * HDIM + d) * 9;
        float w9[9];
#pragma unroll
        for (int t9 = 0; t9 < 9; ++t9) w9[t9] = lw[t9];
        float lb = lepe_b[h * HDIM + d];
#pragma unroll
        for (int r = 0; r < 4; ++r) {
          int m = wv * 16 + l4 * 4 + r;
          if (m < NTOK) {
            int y = m / 7, x0 = m - y * 7;
            float lac = lb;
#pragma unroll
            for (int dy = 0; dy < 3; ++dy) {
#pragma unroll
              for (int dx = 0; dx < 3; ++dx) {
                int yy = y + dy - 1, xx = x0 + dx - 1;
                if (yy >= 0 && yy < 7 && xx >= 0 && xx < 7) {
                  float vvv = __bfloat162float(
                      *(const __hip_bfloat16*)(sm + swzaddr(VT_OFF, d, (yy * 7 + xx) * 2, 128)));
                  lac += w9[dy * 3 + dx] * vvv;
                }
              }
            }
            *(__hip_bfloat16*)(sm + swzaddr(QS_OFF, m, d * 2, 128)) =
                __float2bfloat16(ov[nt][r] + lac);
          }
        }
      }
    }

    // ---------------- P5: proj accumulate: pacc += (O+lepe) @ proj_w[h*56:, :] ----------------
    bf16x8 oa[2];
#pragma unroll
    for (int kt = 0; kt < 2; ++kt)
      oa[kt] = *(const bf16x8*)(sm + swzaddr(QS_OFF, arow, (kt * 32 + l4 * 8) * 2, 128));
#pragma unroll
    for (int nt = 0; nt < 12; ++nt) {
#pragma unroll
      for (int kt = 0; kt < 2; ++kt) {
        bf16x8 pb = *(const bf16x8*)(projwt + (nt * 16 + l15) * 384 + h * HDIM + kt * 32 + l4 * 8);
        pacc[nt] = __builtin_amdgcn_mfma_f32_16x16x32_bf16(oa[kt], pb, pacc[nt], 0, 0, 0);
      }
    }
    __syncthreads();
  }

  // final store
  float* og = out + (size_t)blk * (NTOK * DIMC);
#pragma unroll
  for (int nt = 0; nt < 12; ++nt) {
#pragma unroll
    for (int r = 0; r < 4; ++r) {
      int m = wv * 16 + l4 * 4 + r;
      if (m < NTOK) og[m * DIMC + nt * 16 + l15] = pacc[nt][r];
    }
  }
}

extern "C" void kernel_launch(void* const* d_in, const int* in_sizes, int n_in,
                              void* d_out, int out_size, void* d_ws, size_t ws_size,
                              hipStream_t stream) {
  const float* x      = (const float*)d_in[0];
  const float* mask   = (const float*)d_in[1];
  const float* qkv_w  = (const float*)d_in[2];
  const float* qkv_b  = (const float*)d_in[3];
  const float* tbl    = (const float*)d_in[4];
  const int*   ridx   = (const int*)d_in[5];
  const float* lepe_w = (const float*)d_in[6];
  const float* lepe_b = (const float*)d_in[7];
  const float* proj_w = (const float*)d_in[8];
  const float* proj_b = (const float*)d_in[9];
  unsigned char* ws = (unsigned char*)d_ws;
  float* out = (float*)d_out;

  prep_kernel<<<dim3(1101), dim3(256), 0, stream>>>(qkv_w, proj_w, tbl, ridx, ws);
  winattn_kernel<<<dim3(2048), dim3(256), 0, stream>>>(x, mask, qkv_b, lepe_w, lepe_b,
                                                       proj_b, ws, out);
}

// Round 2
// 1589.350 us; speedup vs baseline: 1.0974x; 1.0974x over previous
//
#include <hip/hip_runtime.h>
#include <hip/hip_bf16.h>

typedef __bf16 bf16x8 __attribute__((ext_vector_type(8)));
typedef float f32x4 __attribute__((ext_vector_type(4)));

#define NTOK 49
#define NH   6
#define HDIM 56
#define DIMC 192
#define SCALE 0.17677669529663687f

// workspace layout (bytes)
#define WS_QKVWT  0          // bf16 [1008][192]  (transposed qkv_w)
#define WS_PROJWT 387072     // bf16 [192][384]   (transposed proj_w, K padded to 384 w/ zeros)
#define WS_BIAS6  534528     // f32  [6][49][49]  (gathered rel bias)

// LDS layout (bytes). ATT region doubles as the bias+mask (bm) table:
// bm is [49][64] bf16 unswizzled, read before att (swizzled) overwrites it.
// Both are row-partitioned identically across waves -> no cross-wave hazard.
#define QS_OFF  0            // bf16 [64][64] swizzled (q, later out+lepe)
#define KS_OFF  8192         // bf16 [64][64] swizzled
#define VT_OFF  16384        // bf16 [64][64] swizzled (v transposed: [d][m])
#define ATT_OFF 24576        // bf16 [64][64] swizzled (P post-softmax) / bm table
#define SMEM_BYTES 32768

__device__ __forceinline__ unsigned swzaddr(unsigned base, int row, int colb, int strideb) {
  return base + (unsigned)((row * strideb + colb) ^ ((row & 7) << 4));
}

__device__ __forceinline__ unsigned short f2bu(float f) {
  __hip_bfloat16 h = __float2bfloat16(f);
  unsigned short u;
  __builtin_memcpy(&u, &h, 2);
  return u;
}

__global__ void prep_kernel(const float* __restrict__ qkv_w,
                            const float* __restrict__ proj_w,
                            const float* __restrict__ tbl,
                            const int* __restrict__ ridx,
                            unsigned char* __restrict__ ws) {
  __hip_bfloat16* qkvwt  = (__hip_bfloat16*)(ws + WS_QKVWT);
  __hip_bfloat16* projwt = (__hip_bfloat16*)(ws + WS_PROJWT);
  float* bias6 = (float*)(ws + WS_BIAS6);
  int idx = blockIdx.x * 256 + threadIdx.x;
  const int n1 = 1008 * 192;
  const int n2 = 192 * 384;
  const int n3 = 6 * 49 * 49;
  if (idx < n1) {
    int c = idx / 192, k = idx - c * 192;
    qkvwt[idx] = __float2bfloat16(qkv_w[k * 1008 + c]);
  } else if (idx < n1 + n2) {
    int j = idx - n1;
    int c = j / 384, kk = j - c * 384;
    projwt[j] = __float2bfloat16(kk < 336 ? proj_w[kk * 192 + c] : 0.0f);
  } else if (idx < n1 + n2 + n3) {
    int j = idx - n1 - n2;
    int h = j / 2401, mn = j - h * 2401;
    bias6[j] = tbl[ridx[mn] * 6 + h];
  }
}

__global__ __launch_bounds__(256, 4) void winattn_kernel(
    const float* __restrict__ x, const float* __restrict__ mask,
    const float* __restrict__ qkv_b, const float* __restrict__ lepe_w,
    const float* __restrict__ lepe_b, const float* __restrict__ proj_b,
    const unsigned char* __restrict__ ws, float* __restrict__ out) {
  __shared__ uint4 smem4[SMEM_BYTES / 16];
  unsigned char* sm = (unsigned char*)smem4;
  const __hip_bfloat16* qkvwt  = (const __hip_bfloat16*)(ws + WS_QKVWT);
  const __hip_bfloat16* projwt = (const __hip_bfloat16*)(ws + WS_PROJWT);
  const float* bias6 = (const float*)(ws + WS_BIAS6);

  const int tid = threadIdx.x;
  const int lane = tid & 63, wv = tid >> 6;
  const int l15 = lane & 15, l4 = lane >> 4;
  const int blk = blockIdx.x;
  const int wdx = blk & 63;

  // zero ALL of LDS once: establishes exact-zero pads (q/k cols 56..63,
  // vt cols 49..63, att rows 49..63) that survive the whole block.
  {
    uint4 z = {0u, 0u, 0u, 0u};
    for (int i = tid; i < SMEM_BYTES / 16; i += 256) smem4[i] = z;
  }

  const int arow = wv * 16 + l15;

  // A-fragments of x loaded DIRECTLY from global (coalesced float4 pairs).
  const float* xg = x + (size_t)blk * (NTOK * DIMC);
  const int xr = arow < NTOK ? arow : NTOK - 1;  // clamp: avoid OOB on last block
  bf16x8 afr[6];
#pragma unroll
  for (int kt = 0; kt < 6; ++kt) {
    const float4* p = (const float4*)(xg + xr * DIMC + kt * 32 + l4 * 8);
    float4 a = p[0], b = p[1];
    union { unsigned short u[8]; bf16x8 v; } pk;
    pk.u[0] = f2bu(a.x); pk.u[1] = f2bu(a.y); pk.u[2] = f2bu(a.z); pk.u[3] = f2bu(a.w);
    pk.u[4] = f2bu(b.x); pk.u[5] = f2bu(b.y); pk.u[6] = f2bu(b.z); pk.u[7] = f2bu(b.w);
    afr[kt] = pk.v;
  }

  // persistent proj accumulators (12 n-tiles of 16 cols = 192)
  f32x4 pacc[12];
#pragma unroll
  for (int nt = 0; nt < 12; ++nt) {
    float pb = proj_b[nt * 16 + l15];
    pacc[nt] = (f32x4){pb, pb, pb, pb};
  }

  const float* maskw = mask + wdx * (NTOK * NTOK);
  __syncthreads();

  for (int h = 0; h < NH; ++h) {
    // -------- stage bm = bias6[h] + mask[wdx] into ATT region (bf16, coalesced) --------
    for (int i = tid; i < NTOK * NTOK; i += 256) {
      int row = i / NTOK, col = i - row * NTOK;
      *(unsigned short*)(sm + ATT_OFF + row * 128 + col * 2) =
          f2bu(bias6[h * (NTOK * NTOK) + i] + maskw[i]);
    }

    // ---------------- P1: qkv = x @ W_h + b  (49 x 168) ----------------
#pragma unroll
    for (int nt = 0; nt < 11; ++nt) {
      int cl = nt * 16 + l15;               // 0..175 (>=168 discarded)
      int cg = h * 168 + cl; if (cg > 1007) cg = 1007;
      float bias = qkv_b[cg];
      f32x4 acc = (f32x4){bias, bias, bias, bias};
#pragma unroll
      for (int kt = 0; kt < 6; ++kt) {
        bf16x8 bf = *(const bf16x8*)(qkvwt + cg * DIMC + kt * 32 + l4 * 8);
        acc = __builtin_amdgcn_mfma_f32_16x16x32_bf16(afr[kt], bf, acc, 0, 0, 0);
      }
      if (cl < 168) {
#pragma unroll
        for (int r = 0; r < 4; ++r) {
          int m = wv * 16 + l4 * 4 + r;
          if (m < NTOK) {
            float vv = acc[r];
            if (cl < 56)
              *(__hip_bfloat16*)(sm + swzaddr(QS_OFF, m, cl * 2, 128)) = __float2bfloat16(vv);
            else if (cl < 112)
              *(__hip_bfloat16*)(sm + swzaddr(KS_OFF, m, (cl - 56) * 2, 128)) = __float2bfloat16(vv);
            else
              *(__hip_bfloat16*)(sm + swzaddr(VT_OFF, cl - 112, m * 2, 128)) = __float2bfloat16(vv);
          }
        }
      }
    }
    __syncthreads();

    // ---------------- P2: S = scale*(q k^T) + bm; softmax ----------------
    bf16x8 qa[2];
#pragma unroll
    for (int kt = 0; kt < 2; ++kt)
      qa[kt] = *(const bf16x8*)(sm + swzaddr(QS_OFF, arow, (kt * 32 + l4 * 8) * 2, 128));
    f32x4 sv[4];
#pragma unroll
    for (int nt = 0; nt < 4; ++nt) {
      f32x4 acc = (f32x4){0.f, 0.f, 0.f, 0.f};
#pragma unroll
      for (int kt = 0; kt < 2; ++kt) {
        bf16x8 kb = *(const bf16x8*)(sm + swzaddr(KS_OFF, nt * 16 + l15, (kt * 32 + l4 * 8) * 2, 128));
        acc = __builtin_amdgcn_mfma_f32_16x16x32_bf16(qa[kt], kb, acc, 0, 0, 0);
      }
      sv[nt] = acc;
    }
#pragma unroll
    for (int nt = 0; nt < 4; ++nt) {
      int n = nt * 16 + l15;
#pragma unroll
      for (int r = 0; r < 4; ++r) {
        int m = wv * 16 + l4 * 4 + r;
        int mc = m < NTOK ? m : NTOK - 1;
        float vv;
        if (n < NTOK) {
          float add = __bfloat162float(
              *(const __hip_bfloat16*)(sm + ATT_OFF + mc * 128 + n * 2));
          vv = SCALE * sv[nt][r] + add;
        } else {
          vv = -1e30f;
        }
        sv[nt][r] = vv;
      }
    }
#pragma unroll
    for (int r = 0; r < 4; ++r) {
      float mx = fmaxf(fmaxf(sv[0][r], sv[1][r]), fmaxf(sv[2][r], sv[3][r]));
      mx = fmaxf(mx, __shfl_xor(mx, 1));
      mx = fmaxf(mx, __shfl_xor(mx, 2));
      mx = fmaxf(mx, __shfl_xor(mx, 4));
      mx = fmaxf(mx, __shfl_xor(mx, 8));
      float p0 = __expf(sv[0][r] - mx), p1 = __expf(sv[1][r] - mx);
      float p2 = __expf(sv[2][r] - mx), p3 = __expf(sv[3][r] - mx);
      float sum = p0 + p1 + p2 + p3;
      sum += __shfl_xor(sum, 1);
      sum += __shfl_xor(sum, 2);
      sum += __shfl_xor(sum, 4);
      sum += __shfl_xor(sum, 8);
      float rinv = 1.0f / sum;
      sv[0][r] = p0 * rinv; sv[1][r] = p1 * rinv; sv[2][r] = p2 * rinv; sv[3][r] = p3 * rinv;
    }
    // att stores overwrite this wave's own bm rows — all bm reads above are done.
#pragma unroll
    for (int nt = 0; nt < 4; ++nt) {
      int n = nt * 16 + l15;
#pragma unroll
      for (int r = 0; r < 4; ++r) {
        int m = wv * 16 + l4 * 4 + r;
        if (m < NTOK)
          *(__hip_bfloat16*)(sm + swzaddr(ATT_OFF, m, n * 2, 128)) = __float2bfloat16(sv[nt][r]);
      }
    }

    // ---------------- P3: O = P @ V  (49 x 56) ----------------
    bf16x8 pa[2];
#pragma unroll
    for (int kt = 0; kt < 2; ++kt)
      pa[kt] = *(const bf16x8*)(sm + swzaddr(ATT_OFF, arow, (kt * 32 + l4 * 8) * 2, 128));
    f32x4 ov[4];
#pragma unroll
    for (int nt = 0; nt < 4; ++nt) {
      f32x4 acc = (f32x4){0.f, 0.f, 0.f, 0.f};
#pragma unroll
      for (int kt = 0; kt < 2; ++kt) {
        bf16x8 vb = *(const bf16x8*)(sm + swzaddr(VT_OFF, nt * 16 + l15, (kt * 32 + l4 * 8) * 2, 128));
        acc = __builtin_amdgcn_mfma_f32_16x16x32_bf16(pa[kt], vb, acc, 0, 0, 0);
      }
      ov[nt] = acc;
    }

    // ---------------- P4: lepe (depthwise 3x3 on v) + store O+lepe into QS region ----------------
#pragma unroll
    for (int nt = 0; nt < 4; ++nt) {
      int d = nt * 16 + l15;
      if (d < HDIM) {
        const float* lw = lepe_w + (h * HDIM + d) * 9;
        float w9[9];
#pragma unroll
        for (int t9 = 0; t9 < 9; ++t9) w9[t9] = lw[t9];
        float lb = lepe_b[h * HDIM + d];
#pragma unroll
        for (int r = 0; r < 4; ++r) {
          int m = wv * 16 + l4 * 4 + r;
          if (m < NTOK) {
            int y = m / 7, x0 = m - y * 7;
            float lac = lb;
#pragma unroll
            for (int dy = 0; dy < 3; ++dy) {
#pragma unroll
              for (int dx = 0; dx < 3; ++dx) {
                int yy = y + dy - 1, xx = x0 + dx - 1;
                if (yy >= 0 && yy < 7 && xx >= 0 && xx < 7) {
                  float vvv = __bfloat162float(
                      *(const __hip_bfloat16*)(sm + swzaddr(VT_OFF, d, (yy * 7 + xx) * 2, 128)));
                  lac += w9[dy * 3 + dx] * vvv;
                }
              }
            }
            *(__hip_bfloat16*)(sm + swzaddr(QS_OFF, m, d * 2, 128)) =
                __float2bfloat16(ov[nt][r] + lac);
          }
        }
      }
    }

    // ---------------- P5: proj accumulate: pacc += (O+lepe) @ proj_w[h*56:, :] ----------------
    bf16x8 oa[2];
#pragma unroll
    for (int kt = 0; kt < 2; ++kt)
      oa[kt] = *(const bf16x8*)(sm + swzaddr(QS_OFF, arow, (kt * 32 + l4 * 8) * 2, 128));
#pragma unroll
    for (int nt = 0; nt < 12; ++nt) {
#pragma unroll
      for (int kt = 0; kt < 2; ++kt) {
        bf16x8 pb = *(const bf16x8*)(projwt + (nt * 16 + l15) * 384 + h * HDIM + kt * 32 + l4 * 8);
        pacc[nt] = __builtin_amdgcn_mfma_f32_16x16x32_bf16(oa[kt], pb, pacc[nt], 0, 0, 0);
      }
    }
    __syncthreads();
  }

  // final store
  float* og = out + (size_t)blk * (NTOK * DIMC);
#pragma unroll
  for (int nt = 0; nt < 12; ++nt) {
#pragma unroll
    for (int r = 0; r < 4; ++r) {
      int m = wv * 16 + l4 * 4 + r;
      if (m < NTOK) og[m * DIMC + nt * 16 + l15] = pacc[nt][r];
    }
  }
}

extern "C" void kernel_launch(void* const* d_in, const int* in_sizes, int n_in,
                              void* d_out, int out_size, void* d_ws, size_t ws_size,
                              hipStream_t stream) {
  const float* x      = (const float*)d_in[0];
  const float* mask   = (const float*)d_in[1];
  const float* qkv_w  = (const float*)d_in[2];
  const float* qkv_b  = (const float*)d_in[3];
  const float* tbl    = (const float*)d_in[4];
  const int*   ridx   = (const int*)d_in[5];
  const float* lepe_w = (const float*)d_in[6];
  const float* lepe_b = (const float*)d_in[7];
  const float* proj_w = (const float*)d_in[8];
  const float* proj_b = (const float*)d_in[9];
  unsigned char* ws = (unsigned char*)d_ws;
  float* out = (float*)d_out;

  prep_kernel<<<dim3(1101), dim3(256), 0, stream>>>(qkv_w, proj_w, tbl, ridx, ws);
  winattn_kernel<<<dim3(2048), dim3(256), 0, stream>>>(x, mask, qkv_b, lepe_w, lepe_b,
                                                       proj_b, ws, out);
}

// Round 4
// 482.973 us; speedup vs baseline: 3.6113x; 3.2908x over previous
//
#include <hip/hip_runtime.h>
#include <hip/hip_bf16.h>

typedef __bf16 bf16x8 __attribute__((ext_vector_type(8)));
typedef float f32x4 __attribute__((ext_vector_type(4)));

#define NTOK 49
#define NH   6
#define HDIM 56
#define DIMC 192
#define SCALE 0.17677669529663687f

// ---------------- workspace layout (bytes) ----------------
// main path:
#define WS_QKVWT  0u          // bf16 [1008][192] transposed qkv_w, q-cols pre-scaled
#define WS_PROJWT 387072u     // bf16 [192][384]  transposed proj_w, K padded 336->384 w/ zeros
#define WS_QKVBS  534528u     // f32  [1008]      qkv_b, q-entries pre-scaled
#define WS_BMALL  538560u     // bf16 [64][6][49][64]  bias+mask pre-summed, col-padded
#define WS_QKV    2947072u    // bf16 [100352][1008]   qkv activations
#define WS_NEED   (WS_QKV + (size_t)100352 * 1008 * 2)   // ~205 MB
// fallback path (R2 layout, 591KB):
#define FB_QKVWT  0
#define FB_PROJWT 387072
#define FB_BIAS6  534528

__device__ __forceinline__ unsigned swzaddr(unsigned base, int row, int colb, int strideb) {
  return base + (unsigned)((row * strideb + colb) ^ ((row & 7) << 4));
}

__device__ __forceinline__ unsigned short f2bu(float f) {
  __hip_bfloat16 h = __float2bfloat16(f);
  unsigned short u;
  __builtin_memcpy(&u, &h, 2);
  return u;
}

// ==================== MAIN PATH ====================

__global__ void prep_main(const float* __restrict__ qkv_w,
                          const float* __restrict__ qkv_b,
                          const float* __restrict__ proj_w,
                          const float* __restrict__ tbl,
                          const int* __restrict__ ridx,
                          const float* __restrict__ mask,
                          unsigned char* __restrict__ ws) {
  __hip_bfloat16* qkvwt  = (__hip_bfloat16*)(ws + WS_QKVWT);
  __hip_bfloat16* projwt = (__hip_bfloat16*)(ws + WS_PROJWT);
  float*          qkvbs  = (float*)(ws + WS_QKVBS);
  __hip_bfloat16* bmall  = (__hip_bfloat16*)(ws + WS_BMALL);
  int idx = blockIdx.x * 256 + threadIdx.x;
  const int n1 = 1008 * 192;       // qkvwt
  const int n2 = 192 * 384;        // projwt
  const int n3 = 1008;             // qkvbs
  const int n4 = 64 * 6 * 49 * 64; // bmall
  if (idx < n1) {
    int c = idx / 192, k = idx - c * 192;
    float v = qkv_w[k * 1008 + c];
    if (c % 168 < 56) v *= SCALE;
    qkvwt[idx] = __float2bfloat16(v);
  } else if (idx < n1 + n2) {
    int j = idx - n1;
    int c = j / 384, kk = j - c * 384;
    projwt[j] = __float2bfloat16(kk < 336 ? proj_w[kk * 192 + c] : 0.0f);
  } else if (idx < n1 + n2 + n3) {
    int c = idx - n1 - n2;
    float v = qkv_b[c];
    if (c % 168 < 56) v *= SCALE;
    qkvbs[c] = v;
  } else if (idx < n1 + n2 + n3 + n4) {
    int j = idx - n1 - n2 - n3;
    int wdx = j / 18816;
    int r1 = j - wdx * 18816;
    int h = r1 / 3136;
    int r2 = r1 - h * 3136;
    int m = r2 >> 6, n = r2 & 63;
    float v = 0.0f;
    if (n < NTOK)
      v = tbl[ridx[m * NTOK + n] * NH + h] + mask[wdx * (NTOK * NTOK) + m * NTOK + n];
    bmall[j] = __float2bfloat16(v);
  }
}

// K1: qkv = x @ Wqkv + b  (M=100352, N=1008, K=192), bf16 out.
// BM=128, BN=144, grid (784, 7). B staged to LDS coalesced; A frags from global x.
__global__ __launch_bounds__(256, 2) void qkv_gemm(
    const float* __restrict__ x, unsigned char* __restrict__ ws) {
  __shared__ uint4 smem4[3456];   // 55296 B: B tile [144][192] bf16 swizzled (stride 384B)
  unsigned char* sm = (unsigned char*)smem4;
  const __hip_bfloat16* qkvwt = (const __hip_bfloat16*)(ws + WS_QKVWT);
  const float* qkvbs = (const float*)(ws + WS_QKVBS);
  unsigned char* qkvbuf = ws + WS_QKV;

  const int tid = threadIdx.x;
  const int lane = tid & 63, wv = tid >> 6;
  const int l15 = lane & 15, l4 = lane >> 4;
  const int mbase = blockIdx.x * 128;
  const int nbase = blockIdx.y * 144;

  // stage B tile: qkvwt rows [nbase, nbase+144), contiguous 55296 B
  {
    const uint4* bsrc = (const uint4*)(qkvwt + nbase * 192);
    for (int j = tid; j < 3456; j += 256) {
      int row = j / 24, c16 = j - row * 24;
      *(uint4*)(sm + swzaddr(0, row, c16 * 16, 384)) = bsrc[j];
    }
  }

  // A fragments: 2 m-tiles x 6 k-tiles, direct from global x (fp32 -> bf16)
  bf16x8 afr[2][6];
#pragma unroll
  for (int mt = 0; mt < 2; ++mt) {
    int g = mbase + wv * 32 + mt * 16 + l15;
    const float* xr = x + (size_t)g * DIMC;
#pragma unroll
    for (int kt = 0; kt < 6; ++kt) {
      const float4* p = (const float4*)(xr + kt * 32 + l4 * 8);
      float4 a = p[0], b = p[1];
      union { unsigned short u[8]; bf16x8 v; } pk;
      pk.u[0] = f2bu(a.x); pk.u[1] = f2bu(a.y); pk.u[2] = f2bu(a.z); pk.u[3] = f2bu(a.w);
      pk.u[4] = f2bu(b.x); pk.u[5] = f2bu(b.y); pk.u[6] = f2bu(b.z); pk.u[7] = f2bu(b.w);
      afr[mt][kt] = pk.v;
    }
  }

  f32x4 acc[2][9];
#pragma unroll
  for (int nt = 0; nt < 9; ++nt) {
    float b = qkvbs[nbase + nt * 16 + l15];
    acc[0][nt] = (f32x4){b, b, b, b};
    acc[1][nt] = (f32x4){b, b, b, b};
  }
  __syncthreads();

#pragma unroll
  for (int kt = 0; kt < 6; ++kt) {
#pragma unroll
    for (int nt = 0; nt < 9; ++nt) {
      bf16x8 bf = *(const bf16x8*)(sm + swzaddr(0, nt * 16 + l15, kt * 64 + l4 * 16, 384));
      acc[0][nt] = __builtin_amdgcn_mfma_f32_16x16x32_bf16(afr[0][kt], bf, acc[0][nt], 0, 0, 0);
      acc[1][nt] = __builtin_amdgcn_mfma_f32_16x16x32_bf16(afr[1][kt], bf, acc[1][nt], 0, 0, 0);
    }
  }
  __syncthreads();

  // dump C (bf16) into LDS (B region dead), then coalesced copy-out
#pragma unroll
  for (int mt = 0; mt < 2; ++mt)
#pragma unroll
    for (int nt = 0; nt < 9; ++nt)
#pragma unroll
      for (int r = 0; r < 4; ++r) {
        int row = wv * 32 + mt * 16 + l4 * 4 + r;
        *(unsigned short*)(sm + swzaddr(0, row, (nt * 16 + l15) * 2, 384)) =
            f2bu(acc[mt][nt][r]);
      }
  __syncthreads();
  for (int j = tid; j < 2304; j += 256) {
    int row = j / 18, c16 = j - row * 18;
    uint4 v = *(const uint4*)(sm + swzaddr(0, row, c16 * 16, 384));
    *(uint4*)(qkvbuf + (size_t)(mbase + row) * 2016 + nbase * 2 + c16 * 16) = v;
  }
}

// K2: per-window attention (6 heads) + lepe + proj, qkv read from ws.
// LDS: KS[64][64] 8K | VT[64][64] 8K | ATT[64][64] 8K | OALL[64][384] 48K  (73728 B)
// PROJB overlays KS+VT (12288 B) during proj phase.
#define K2_KS   0u
#define K2_VT   8192u
#define K2_ATT  16384u
#define K2_OALL 24576u
#define K2_SMEM 73728u

__global__ __launch_bounds__(256, 2) void attn_proj(
    const float* __restrict__ lepe_w, const float* __restrict__ lepe_b,
    const float* __restrict__ proj_b, unsigned char* __restrict__ ws,
    float* __restrict__ out) {
  __shared__ uint4 smem4[K2_SMEM / 16];
  unsigned char* sm = (unsigned char*)smem4;
  const __hip_bfloat16* projwt = (const __hip_bfloat16*)(ws + WS_PROJWT);
  const unsigned char* bmall = ws + WS_BMALL;
  const unsigned char* qkvbuf = ws + WS_QKV;

  const int tid = threadIdx.x;
  const int lane = tid & 63, wv = tid >> 6;
  const int l15 = lane & 15, l4 = lane >> 4;
  const int blk = blockIdx.x;
  const int wdx = blk & 63;

  // zero all LDS once (pads stay zero for the whole block)
  {
    uint4 z = {0u, 0u, 0u, 0u};
    for (int i = tid; i < K2_SMEM / 16; i += 256) smem4[i] = z;
  }

  f32x4 acc[12];
#pragma unroll
  for (int nt = 0; nt < 12; ++nt) {
    float pb = proj_b[nt * 16 + l15];
    acc[nt] = (f32x4){pb, pb, pb, pb};
  }

  const unsigned char* qbase = qkvbuf + (size_t)blk * (NTOK * 2016);
  const int arow = wv * 16 + l15;
  const int xr = arow < NTOK ? arow : NTOK - 1;
  __syncthreads();

  for (int h = 0; h < NH; ++h) {
    // ---- stage k (swizzled KS[m][d]) and v (transposed VT[d][m]) and bm (ATT) ----
    for (int j = tid; j < 343; j += 256) {
      int m = j / 7, c = j - m * 7;
      uint4 kv = *(const uint4*)(qbase + (size_t)m * 2016 + 336 * h + 112 + c * 16);
      *(uint4*)(sm + swzaddr(K2_KS, m, c * 16, 128)) = kv;
      uint4 vv = *(const uint4*)(qbase + (size_t)m * 2016 + 336 * h + 224 + c * 16);
      union { uint4 q; unsigned short u[8]; } pk; pk.q = vv;
#pragma unroll
      for (int e = 0; e < 8; ++e)
        *(unsigned short*)(sm + swzaddr(K2_VT, c * 8 + e, m * 2, 128)) = pk.u[e];
    }
    {
      const uint4* bmsrc = (const uint4*)(bmall + (size_t)(wdx * 6 + h) * 6272);
      for (int j = tid; j < 392; j += 256) {
        int m = j >> 3, c = j & 7;
        *(uint4*)(sm + K2_ATT + m * 128 + c * 16) = bmsrc[j];
      }
    }
    // q fragments direct from global (L2-hot: same 99KB slice)
    bf16x8 qa[2];
#pragma unroll
    for (int kt = 0; kt < 2; ++kt)
      qa[kt] = *(const bf16x8*)(qbase + (size_t)xr * 2016 + 336 * h + kt * 64 + l4 * 16);
    __syncthreads();

    // ---- S = q k^T + bm ; softmax ----
    f32x4 sv[4];
#pragma unroll
    for (int nt = 0; nt < 4; ++nt) {
      f32x4 a0 = (f32x4){0.f, 0.f, 0.f, 0.f};
#pragma unroll
      for (int kt = 0; kt < 2; ++kt) {
        bf16x8 kb = *(const bf16x8*)(sm + swzaddr(K2_KS, nt * 16 + l15, kt * 64 + l4 * 16, 128));
        a0 = __builtin_amdgcn_mfma_f32_16x16x32_bf16(qa[kt], kb, a0, 0, 0, 0);
      }
      sv[nt] = a0;
    }
#pragma unroll
    for (int nt = 0; nt < 4; ++nt) {
      int n = nt * 16 + l15;
#pragma unroll
      for (int r = 0; r < 4; ++r) {
        int m = wv * 16 + l4 * 4 + r;
        int mc = m < NTOK ? m : NTOK - 1;
        if (n < NTOK) {
          float add = __bfloat162float(
              *(const __hip_bfloat16*)(sm + K2_ATT + mc * 128 + n * 2));
          sv[nt][r] = sv[nt][r] + add;
        } else {
          sv[nt][r] = -1e30f;
        }
      }
    }
#pragma unroll
    for (int r = 0; r < 4; ++r) {
      float mx = fmaxf(fmaxf(sv[0][r], sv[1][r]), fmaxf(sv[2][r], sv[3][r]));
      mx = fmaxf(mx, __shfl_xor(mx, 1));
      mx = fmaxf(mx, __shfl_xor(mx, 2));
      mx = fmaxf(mx, __shfl_xor(mx, 4));
      mx = fmaxf(mx, __shfl_xor(mx, 8));
      float p0 = __expf(sv[0][r] - mx), p1 = __expf(sv[1][r] - mx);
      float p2 = __expf(sv[2][r] - mx), p3 = __expf(sv[3][r] - mx);
      float sum = p0 + p1 + p2 + p3;
      sum += __shfl_xor(sum, 1);
      sum += __shfl_xor(sum, 2);
      sum += __shfl_xor(sum, 4);
      sum += __shfl_xor(sum, 8);
      float rinv = 1.0f / sum;
      sv[0][r] = p0 * rinv; sv[1][r] = p1 * rinv; sv[2][r] = p2 * rinv; sv[3][r] = p3 * rinv;
    }
    // write P (own rows only; same-wave in-order DS => no barrier needed before reads)
#pragma unroll
    for (int nt = 0; nt < 4; ++nt) {
      int n = nt * 16 + l15;
#pragma unroll
      for (int r = 0; r < 4; ++r) {
        int m = wv * 16 + l4 * 4 + r;
        if (m < NTOK)
          *(__hip_bfloat16*)(sm + swzaddr(K2_ATT, m, n * 2, 128)) = __float2bfloat16(sv[nt][r]);
      }
    }

    // ---- O = P @ V ----
    bf16x8 pa[2];
#pragma unroll
    for (int kt = 0; kt < 2; ++kt)
      pa[kt] = *(const bf16x8*)(sm + swzaddr(K2_ATT, arow, kt * 64 + l4 * 16, 128));
    f32x4 ov[4];
#pragma unroll
    for (int nt = 0; nt < 4; ++nt) {
      f32x4 a0 = (f32x4){0.f, 0.f, 0.f, 0.f};
#pragma unroll
      for (int kt = 0; kt < 2; ++kt) {
        bf16x8 vb = *(const bf16x8*)(sm + swzaddr(K2_VT, nt * 16 + l15, kt * 64 + l4 * 16, 128));
        a0 = __builtin_amdgcn_mfma_f32_16x16x32_bf16(pa[kt], vb, a0, 0, 0, 0);
      }
      ov[nt] = a0;
    }

    // ---- lepe + store O+lepe into OALL[m][h*56+d] ----
#pragma unroll
    for (int nt = 0; nt < 4; ++nt) {
      int d = nt * 16 + l15;
      if (d < HDIM) {
        const float* lw = lepe_w + (h * HDIM + d) * 9;
        float w9[9];
#pragma unroll
        for (int t9 = 0; t9 < 9; ++t9) w9[t9] = lw[t9];
        float lb = lepe_b[h * HDIM + d];
#pragma unroll
        for (int r = 0; r < 4; ++r) {
          int m = wv * 16 + l4 * 4 + r;
          if (m < NTOK) {
            int y = m / 7, x0 = m - y * 7;
            float lac = lb;
#pragma unroll
            for (int dy = 0; dy < 3; ++dy)
#pragma unroll
              for (int dx = 0; dx < 3; ++dx) {
                int yy = y + dy - 1, xx = x0 + dx - 1;
                if (yy >= 0 && yy < 7 && xx >= 0 && xx < 7) {
                  float vvv = __bfloat162float(
                      *(const __hip_bfloat16*)(sm + swzaddr(K2_VT, d, (yy * 7 + xx) * 2, 128)));
                  lac += w9[dy * 3 + dx] * vvv;
                }
              }
            *(__hip_bfloat16*)(sm + swzaddr(K2_OALL, m, (h * HDIM + d) * 2, 768)) =
                __float2bfloat16(ov[nt][r] + lac);
          }
        }
      }
    }
    __syncthreads();
  }

  // ---- proj: out = OALL @ projwt + b, B chunks staged per k-step ----
  for (int kt = 0; kt < 11; ++kt) {
    // stage projwt[:, kt*32 .. +32): 192 rows x 64 B -> PROJB (stride 64, no swizzle)
    for (int j = tid; j < 768; j += 256) {
      int n = j >> 2, c = j & 3;
      uint4 v = *(const uint4*)((const unsigned char*)projwt + (size_t)n * 768 + kt * 64 + c * 16);
      *(uint4*)(sm + (unsigned)(n * 64 + c * 16)) = v;
    }
    bf16x8 oa = *(const bf16x8*)(sm + swzaddr(K2_OALL, arow, kt * 64 + l4 * 16, 768));
    __syncthreads();
#pragma unroll
    for (int nt = 0; nt < 12; ++nt) {
      bf16x8 pb = *(const bf16x8*)(sm + (unsigned)((nt * 16 + l15) * 64 + l4 * 16));
      acc[nt] = __builtin_amdgcn_mfma_f32_16x16x32_bf16(oa, pb, acc[nt], 0, 0, 0);
    }
    __syncthreads();
  }

  // ---- epilogue: dump fp32 C into OALL region, then full-line copy-out ----
#pragma unroll
  for (int nt = 0; nt < 12; ++nt)
#pragma unroll
    for (int r = 0; r < 4; ++r) {
      int m = wv * 16 + l4 * 4 + r;
      *(float*)(sm + swzaddr(K2_OALL, m, (nt * 16 + l15) * 4, 768)) = acc[nt][r];
    }
  __syncthreads();
  {
    unsigned char* og = (unsigned char*)out + (size_t)blk * 37632;
    for (int j = tid; j < 2352; j += 256) {
      int row = j / 48, c16 = j - row * 48;
      uint4 v = *(const uint4*)(sm + swzaddr(K2_OALL, row, c16 * 16, 768));
      *(uint4*)(og + row * 768 + c16 * 16) = v;
    }
  }
}

// ==================== FALLBACK PATH (R2 kernel, verbatim) ====================

__global__ void prep_fb(const float* __restrict__ qkv_w,
                        const float* __restrict__ proj_w,
                        const float* __restrict__ tbl,
                        const int* __restrict__ ridx,
                        unsigned char* __restrict__ ws) {
  __hip_bfloat16* qkvwt  = (__hip_bfloat16*)(ws + FB_QKVWT);
  __hip_bfloat16* projwt = (__hip_bfloat16*)(ws + FB_PROJWT);
  float* bias6 = (float*)(ws + FB_BIAS6);
  int idx = blockIdx.x * 256 + threadIdx.x;
  const int n1 = 1008 * 192;
  const int n2 = 192 * 384;
  const int n3 = 6 * 49 * 49;
  if (idx < n1) {
    int c = idx / 192, k = idx - c * 192;
    qkvwt[idx] = __float2bfloat16(qkv_w[k * 1008 + c]);
  } else if (idx < n1 + n2) {
    int j = idx - n1;
    int c = j / 384, kk = j - c * 384;
    projwt[j] = __float2bfloat16(kk < 336 ? proj_w[kk * 192 + c] : 0.0f);
  } else if (idx < n1 + n2 + n3) {
    int j = idx - n1 - n2;
    int h = j / 2401, mn = j - h * 2401;
    bias6[j] = tbl[ridx[mn] * 6 + h];
  }
}

#define QS_OFF  0
#define KS_OFF  8192
#define VT_OFF  16384
#define ATT_OFF 24576
#define SMEM_BYTES 32768

__global__ __launch_bounds__(256, 4) void winattn_fb(
    const float* __restrict__ x, const float* __restrict__ mask,
    const float* __restrict__ qkv_b, const float* __restrict__ lepe_w,
    const float* __restrict__ lepe_b, const float* __restrict__ proj_b,
    const unsigned char* __restrict__ ws, float* __restrict__ out) {
  __shared__ uint4 smem4[SMEM_BYTES / 16];
  unsigned char* sm = (unsigned char*)smem4;
  const __hip_bfloat16* qkvwt  = (const __hip_bfloat16*)(ws + FB_QKVWT);
  const __hip_bfloat16* projwt = (const __hip_bfloat16*)(ws + FB_PROJWT);
  const float* bias6 = (const float*)(ws + FB_BIAS6);

  const int tid = threadIdx.x;
  const int lane = tid & 63, wv = tid >> 6;
  const int l15 = lane & 15, l4 = lane >> 4;
  const int blk = blockIdx.x;
  const int wdx = blk & 63;
  {
    uint4 z = {0u, 0u, 0u, 0u};
    for (int i = tid; i < SMEM_BYTES / 16; i += 256) smem4[i] = z;
  }
  const int arow = wv * 16 + l15;
  const float* xg = x + (size_t)blk * (NTOK * DIMC);
  const int xr = arow < NTOK ? arow : NTOK - 1;
  bf16x8 afr[6];
#pragma unroll
  for (int kt = 0; kt < 6; ++kt) {
    const float4* p = (const float4*)(xg + xr * DIMC + kt * 32 + l4 * 8);
    float4 a = p[0], b = p[1];
    union { unsigned short u[8]; bf16x8 v; } pk;
    pk.u[0] = f2bu(a.x); pk.u[1] = f2bu(a.y); pk.u[2] = f2bu(a.z); pk.u[3] = f2bu(a.w);
    pk.u[4] = f2bu(b.x); pk.u[5] = f2bu(b.y); pk.u[6] = f2bu(b.z); pk.u[7] = f2bu(b.w);
    afr[kt] = pk.v;
  }
  f32x4 pacc[12];
#pragma unroll
  for (int nt = 0; nt < 12; ++nt) {
    float pb = proj_b[nt * 16 + l15];
    pacc[nt] = (f32x4){pb, pb, pb, pb};
  }
  const float* maskw = mask + wdx * (NTOK * NTOK);
  __syncthreads();

  for (int h = 0; h < NH; ++h) {
    for (int i = tid; i < NTOK * NTOK; i += 256) {
      int row = i / NTOK, col = i - row * NTOK;
      *(unsigned short*)(sm + ATT_OFF + row * 128 + col * 2) =
          f2bu(bias6[h * (NTOK * NTOK) + i] + maskw[i]);
    }
#pragma unroll
    for (int nt = 0; nt < 11; ++nt) {
      int cl = nt * 16 + l15;
      int cg = h * 168 + cl; if (cg > 1007) cg = 1007;
      float bias = qkv_b[cg];
      f32x4 acc = (f32x4){bias, bias, bias, bias};
#pragma unroll
      for (int kt = 0; kt < 6; ++kt) {
        bf16x8 bf = *(const bf16x8*)(qkvwt + cg * DIMC + kt * 32 + l4 * 8);
        acc = __builtin_amdgcn_mfma_f32_16x16x32_bf16(afr[kt], bf, acc, 0, 0, 0);
      }
      if (cl < 168) {
#pragma unroll
        for (int r = 0; r < 4; ++r) {
          int m = wv * 16 + l4 * 4 + r;
          if (m < NTOK) {
            float vv = acc[r];
            if (cl < 56)
              *(__hip_bfloat16*)(sm + swzaddr(QS_OFF, m, cl * 2, 128)) = __float2bfloat16(vv);
            else if (cl < 112)
              *(__hip_bfloat16*)(sm + swzaddr(KS_OFF, m, (cl - 56) * 2, 128)) = __float2bfloat16(vv);
            else
              *(__hip_bfloat16*)(sm + swzaddr(VT_OFF, cl - 112, m * 2, 128)) = __float2bfloat16(vv);
          }
        }
      }
    }
    __syncthreads();
    bf16x8 qa[2];
#pragma unroll
    for (int kt = 0; kt < 2; ++kt)
      qa[kt] = *(const bf16x8*)(sm + swzaddr(QS_OFF, arow, (kt * 32 + l4 * 8) * 2, 128));
    f32x4 sv[4];
#pragma unroll
    for (int nt = 0; nt < 4; ++nt) {
      f32x4 acc = (f32x4){0.f, 0.f, 0.f, 0.f};
#pragma unroll
      for (int kt = 0; kt < 2; ++kt) {
        bf16x8 kb = *(const bf16x8*)(sm + swzaddr(KS_OFF, nt * 16 + l15, (kt * 32 + l4 * 8) * 2, 128));
        acc = __builtin_amdgcn_mfma_f32_16x16x32_bf16(qa[kt], kb, acc, 0, 0, 0);
      }
      sv[nt] = acc;
    }
#pragma unroll
    for (int nt = 0; nt < 4; ++nt) {
      int n = nt * 16 + l15;
#pragma unroll
      for (int r = 0; r < 4; ++r) {
        int m = wv * 16 + l4 * 4 + r;
        int mc = m < NTOK ? m : NTOK - 1;
        float vv;
        if (n < NTOK) {
          float add = __bfloat162float(
              *(const __hip_bfloat16*)(sm + ATT_OFF + mc * 128 + n * 2));
          vv = SCALE * sv[nt][r] + add;
        } else {
          vv = -1e30f;
        }
        sv[nt][r] = vv;
      }
    }
#pragma unroll
    for (int r = 0; r < 4; ++r) {
      float mx = fmaxf(fmaxf(sv[0][r], sv[1][r]), fmaxf(sv[2][r], sv[3][r]));
      mx = fmaxf(mx, __shfl_xor(mx, 1));
      mx = fmaxf(mx, __shfl_xor(mx, 2));
      mx = fmaxf(mx, __shfl_xor(mx, 4));
      mx = fmaxf(mx, __shfl_xor(mx, 8));
      float p0 = __expf(sv[0][r] - mx), p1 = __expf(sv[1][r] - mx);
      float p2 = __expf(sv[2][r] - mx), p3 = __expf(sv[3][r] - mx);
      float sum = p0 + p1 + p2 + p3;
      sum += __shfl_xor(sum, 1);
      sum += __shfl_xor(sum, 2);
      sum += __shfl_xor(sum, 4);
      sum += __shfl_xor(sum, 8);
      float rinv = 1.0f / sum;
      sv[0][r] = p0 * rinv; sv[1][r] = p1 * rinv; sv[2][r] = p2 * rinv; sv[3][r] = p3 * rinv;
    }
#pragma unroll
    for (int nt = 0; nt < 4; ++nt) {
      int n = nt * 16 + l15;
#pragma unroll
      for (int r = 0; r < 4; ++r) {
        int m = wv * 16 + l4 * 4 + r;
        if (m < NTOK)
          *(__hip_bfloat16*)(sm + swzaddr(ATT_OFF, m, n * 2, 128)) = __float2bfloat16(sv[nt][r]);
      }
    }
    bf16x8 pa[2];
#pragma unroll
    for (int kt = 0; kt < 2; ++kt)
      pa[kt] = *(const bf16x8*)(sm + swzaddr(ATT_OFF, arow, (kt * 32 + l4 * 8) * 2, 128));
    f32x4 ov[4];
#pragma unroll
    for (int nt = 0; nt < 4; ++nt) {
      f32x4 acc = (f32x4){0.f, 0.f, 0.f, 0.f};
#pragma unroll
      for (int kt = 0; kt < 2; ++kt) {
        bf16x8 vb = *(const bf16x8*)(sm + swzaddr(VT_OFF, nt * 16 + l15, (kt * 32 + l4 * 8) * 2, 128));
        acc = __builtin_amdgcn_mfma_f32_16x16x32_bf16(pa[kt], vb, acc, 0, 0, 0);
      }
      ov[nt] = acc;
    }
#pragma unroll
    for (int nt = 0; nt < 4; ++nt) {
      int d = nt * 16 + l15;
      if (d < HDIM) {
        const float* lw = lepe_w + (h * HDIM + d) * 9;
        float w9[9];
#pragma unroll
        for (int t9 = 0; t9 < 9; ++t9) w9[t9] = lw[t9];
        float lb = lepe_b[h * HDIM + d];
#pragma unroll
        for (int r = 0; r < 4; ++r) {
          int m = wv * 16 + l4 * 4 + r;
          if (m < NTOK) {
            int y = m / 7, x0 = m - y * 7;
            float lac = lb;
#pragma unroll
            for (int dy = 0; dy < 3; ++dy)
#pragma unroll
              for (int dx = 0; dx < 3; ++dx) {
                int yy = y + dy - 1, xx = x0 + dx - 1;
                if (yy >= 0 && yy < 7 && xx >= 0 && xx < 7) {
                  float vvv = __bfloat162float(
                      *(const __hip_bfloat16*)(sm + swzaddr(VT_OFF, d, (yy * 7 + xx) * 2, 128)));
                  lac += w9[dy * 3 + dx] * vvv;
                }
              }
            *(__hip_bfloat16*)(sm + swzaddr(QS_OFF, m, d * 2, 128)) =
                __float2bfloat16(ov[nt][r] + lac);
          }
        }
      }
    }
    bf16x8 oa[2];
#pragma unroll
    for (int kt = 0; kt < 2; ++kt)
      oa[kt] = *(const bf16x8*)(sm + swzaddr(QS_OFF, arow, (kt * 32 + l4 * 8) * 2, 128));
#pragma unroll
    for (int nt = 0; nt < 12; ++nt) {
#pragma unroll
      for (int kt = 0; kt < 2; ++kt) {
        bf16x8 pb = *(const bf16x8*)(projwt + (nt * 16 + l15) * 384 + h * HDIM + kt * 32 + l4 * 8);
        pacc[nt] = __builtin_amdgcn_mfma_f32_16x16x32_bf16(oa[kt], pb, pacc[nt], 0, 0, 0);
      }
    }
    __syncthreads();
  }
  float* og = out + (size_t)blk * (NTOK * DIMC);
#pragma unroll
  for (int nt = 0; nt < 12; ++nt) {
#pragma unroll
    for (int r = 0; r < 4; ++r) {
      int m = wv * 16 + l4 * 4 + r;
      if (m < NTOK) og[m * DIMC + nt * 16 + l15] = pacc[nt][r];
    }
  }
}

// ==================== launcher ====================

extern "C" void kernel_launch(void* const* d_in, const int* in_sizes, int n_in,
                              void* d_out, int out_size, void* d_ws, size_t ws_size,
                              hipStream_t stream) {
  const float* x      = (const float*)d_in[0];
  const float* mask   = (const float*)d_in[1];
  const float* qkv_w  = (const float*)d_in[2];
  const float* qkv_b  = (const float*)d_in[3];
  const float* tbl    = (const float*)d_in[4];
  const int*   ridx   = (const int*)d_in[5];
  const float* lepe_w = (const float*)d_in[6];
  const float* lepe_b = (const float*)d_in[7];
  const float* proj_w = (const float*)d_in[8];
  const float* proj_b = (const float*)d_in[9];
  unsigned char* ws = (unsigned char*)d_ws;
  float* out = (float*)d_out;

  if (ws_size >= WS_NEED) {
    const int n_prep = 1008 * 192 + 192 * 384 + 1008 + 64 * 6 * 49 * 64;
    prep_main<<<dim3((n_prep + 255) / 256), dim3(256), 0, stream>>>(
        qkv_w, qkv_b, proj_w, tbl, ridx, mask, ws);
    qkv_gemm<<<dim3(784, 7), dim3(256), 0, stream>>>(x, ws);
    attn_proj<<<dim3(2048), dim3(256), 0, stream>>>(lepe_w, lepe_b, proj_b, ws, out);
  } else {
    prep_fb<<<dim3(1101), dim3(256), 0, stream>>>(qkv_w, proj_w, tbl, ridx, ws);
    winattn_fb<<<dim3(2048), dim3(256), 0, stream>>>(x, mask, qkv_b, lepe_w, lepe_b,
                                                     proj_b, ws, out);
  }
}

// Round 5
// 438.887 us; speedup vs baseline: 3.9741x; 1.1004x over previous
//
#include <hip/hip_runtime.h>
#include <hip/hip_bf16.h>

typedef __bf16 bf16x8 __attribute__((ext_vector_type(8)));
typedef float f32x4 __attribute__((ext_vector_type(4)));

#define NTOK 49
#define NH   6
#define HDIM 56
#define DIMC 192
#define SCALE 0.17677669529663687f

// ---------------- workspace layout (bytes) ----------------
// main path:
#define WS_QKVWT   0u          // bf16 [1008][192] transposed qkv_w, q-cols pre-scaled
#define WS_PROJWT  387072u     // bf16 [192][352]  transposed proj_w, K padded 336->352 w/ zeros
#define WS_QKVBS   522240u     // f32  [1008]      qkv_b, q-entries pre-scaled
#define WS_BMALLT  526272u     // bf16 [64][6][64 n][64 m] transposed bias+mask, swizzle-ready
#define WS_QKV     3672000u    // bf16 [100352][1008] qkv activations (q-slot later holds O+lepe)
#define WS_NEED    (WS_QKV + (size_t)100352 * 2016 + 4096)   // ~206 MB (+slack for tail OOB-reads)
// fallback path (R2 layout, 591KB):
#define FB_QKVWT  0
#define FB_PROJWT 387072
#define FB_BIAS6  534528

__device__ __forceinline__ unsigned swzaddr(unsigned base, int row, int colb, int strideb) {
  return base + (unsigned)((row * strideb + colb) ^ ((row & 7) << 4));
}

__device__ __forceinline__ unsigned short f2bu(float f) {
  __hip_bfloat16 h = __float2bfloat16(f);
  unsigned short u;
  __builtin_memcpy(&u, &h, 2);
  return u;
}

// ==================== MAIN PATH ====================

__global__ void prep_main(const float* __restrict__ qkv_w,
                          const float* __restrict__ qkv_b,
                          const float* __restrict__ proj_w,
                          const float* __restrict__ tbl,
                          const int* __restrict__ ridx,
                          const float* __restrict__ mask,
                          unsigned char* __restrict__ ws) {
  __hip_bfloat16* qkvwt   = (__hip_bfloat16*)(ws + WS_QKVWT);
  __hip_bfloat16* projwt2 = (__hip_bfloat16*)(ws + WS_PROJWT);
  float*          qkvbs   = (float*)(ws + WS_QKVBS);
  __hip_bfloat16* bmallT  = (__hip_bfloat16*)(ws + WS_BMALLT);
  int idx = blockIdx.x * 256 + threadIdx.x;
  const int n1 = 1008 * 192;        // qkvwt
  const int n2 = 192 * 352;         // projwt2
  const int n3 = 1008;              // qkvbs
  const int n4 = 64 * 6 * 64 * 64;  // bmallT
  if (idx < n1) {
    int c = idx / 192, k = idx - c * 192;
    float v = qkv_w[k * 1008 + c];
    if (c % 168 < 56) v *= SCALE;
    qkvwt[idx] = __float2bfloat16(v);
  } else if (idx < n1 + n2) {
    int j = idx - n1;
    int n = j / 352, kk = j - n * 352;
    projwt2[j] = __float2bfloat16(kk < 336 ? proj_w[kk * 192 + n] : 0.0f);
  } else if (idx < n1 + n2 + n3) {
    int c = idx - n1 - n2;
    float v = qkv_b[c];
    if (c % 168 < 56) v *= SCALE;
    qkvbs[c] = v;
  } else if (idx < n1 + n2 + n3 + n4) {
    int j = idx - n1 - n2 - n3;
    int wh = j >> 12;            // / 4096
    int e = j & 4095;
    int n = e >> 6, m = e & 63;
    int wdx = wh / 6, h = wh - wdx * 6;
    float v;
    if (n >= NTOK) v = -1e30f;         // pad-col masking folded in
    else if (m >= NTOK) v = 0.0f;
    else v = tbl[ridx[m * NTOK + n] * NH + h] + mask[wdx * (NTOK * NTOK) + m * NTOK + n];
    bmallT[j] = __float2bfloat16(v);
  }
}

// K1: qkv = x @ Wqkv + b  (M=100352, N=1008, K=192), bf16 out.
// grid (7, 784): consecutive blocks share A rows -> x read ~1x via L2.
__global__ __launch_bounds__(256, 2) void qkv_gemm(
    const float* __restrict__ x, unsigned char* __restrict__ ws) {
  __shared__ uint4 smem4[3456];   // 55296 B: B tile [144][192] bf16 swizzled (stride 384B)
  unsigned char* sm = (unsigned char*)smem4;
  const __hip_bfloat16* qkvwt = (const __hip_bfloat16*)(ws + WS_QKVWT);
  const float* qkvbs = (const float*)(ws + WS_QKVBS);
  unsigned char* qkvbuf = ws + WS_QKV;

  const int tid = threadIdx.x;
  const int lane = tid & 63, wv = tid >> 6;
  const int l15 = lane & 15, l4 = lane >> 4;
  const int nbase = blockIdx.x * 144;
  const int mbase = blockIdx.y * 128;

  {
    const uint4* bsrc = (const uint4*)(qkvwt + nbase * 192);
    for (int j = tid; j < 3456; j += 256) {
      int row = j / 24, c16 = j - row * 24;
      *(uint4*)(sm + swzaddr(0, row, c16 * 16, 384)) = bsrc[j];
    }
  }

  bf16x8 afr[2][6];
#pragma unroll
  for (int mt = 0; mt < 2; ++mt) {
    int g = mbase + wv * 32 + mt * 16 + l15;
    const float* xr = x + (size_t)g * DIMC;
#pragma unroll
    for (int kt = 0; kt < 6; ++kt) {
      const float4* p = (const float4*)(xr + kt * 32 + l4 * 8);
      float4 a = p[0], b = p[1];
      union { unsigned short u[8]; bf16x8 v; } pk;
      pk.u[0] = f2bu(a.x); pk.u[1] = f2bu(a.y); pk.u[2] = f2bu(a.z); pk.u[3] = f2bu(a.w);
      pk.u[4] = f2bu(b.x); pk.u[5] = f2bu(b.y); pk.u[6] = f2bu(b.z); pk.u[7] = f2bu(b.w);
      afr[mt][kt] = pk.v;
    }
  }

  f32x4 acc[2][9];
#pragma unroll
  for (int nt = 0; nt < 9; ++nt) {
    float b = qkvbs[nbase + nt * 16 + l15];
    acc[0][nt] = (f32x4){b, b, b, b};
    acc[1][nt] = (f32x4){b, b, b, b};
  }
  __syncthreads();

#pragma unroll
  for (int kt = 0; kt < 6; ++kt) {
#pragma unroll
    for (int nt = 0; nt < 9; ++nt) {
      bf16x8 bf = *(const bf16x8*)(sm + swzaddr(0, nt * 16 + l15, kt * 64 + l4 * 16, 384));
      acc[0][nt] = __builtin_amdgcn_mfma_f32_16x16x32_bf16(afr[0][kt], bf, acc[0][nt], 0, 0, 0);
      acc[1][nt] = __builtin_amdgcn_mfma_f32_16x16x32_bf16(afr[1][kt], bf, acc[1][nt], 0, 0, 0);
    }
  }
  __syncthreads();

#pragma unroll
  for (int mt = 0; mt < 2; ++mt)
#pragma unroll
    for (int nt = 0; nt < 9; ++nt)
#pragma unroll
      for (int r = 0; r < 4; ++r) {
        int row = wv * 32 + mt * 16 + l4 * 4 + r;
        *(unsigned short*)(sm + swzaddr(0, row, (nt * 16 + l15) * 2, 384)) =
            f2bu(acc[mt][nt][r]);
      }
  __syncthreads();
  for (int j = tid; j < 2304; j += 256) {
    int row = j / 18, c16 = j - row * 18;
    uint4 v = *(const uint4*)(sm + swzaddr(0, row, c16 * 16, 384));
    *(uint4*)(qkvbuf + (size_t)(mbase + row) * 2016 + nbase * 2 + c16 * 16) = v;
  }
}

// K2: one block per (head, window). LDS: KS 8K (later O-dump) | VT 8K | BMT 8K | ATT 8K.
#define A_KS   0u
#define A_VT   8192u
#define A_BMT  16384u
#define A_ATT  24576u
#define A_SMEM 32768u

__global__ __launch_bounds__(256, 4) void attn_head(
    const float* __restrict__ lepe_w, const float* __restrict__ lepe_b,
    unsigned char* __restrict__ ws) {
  __shared__ uint4 smem4[A_SMEM / 16];
  unsigned char* sm = (unsigned char*)smem4;
  const unsigned char* bmallT = ws + WS_BMALLT;
  unsigned char* qkvbuf = ws + WS_QKV;

  const int tid = threadIdx.x;
  const int lane = tid & 63, wv = tid >> 6;
  const int l15 = lane & 15, l4 = lane >> 4;
  const int h = blockIdx.x;
  const int win = blockIdx.y;
  const int wdx = win & 63;
  unsigned char* qbase = qkvbuf + (size_t)win * (NTOK * 2016);

  // zero all LDS (pads must be exact 0, never stale/NaN)
  {
    uint4 z = {0u, 0u, 0u, 0u};
    for (int i = tid; i < A_SMEM / 16; i += 256) smem4[i] = z;
  }
  __syncthreads();

  // stage k (KS rows) + v (VT transposed) for this head
  for (int j = tid; j < 343; j += 256) {
    int m = j / 7, c = j - m * 7;
    uint4 kv = *(const uint4*)(qbase + (size_t)m * 2016 + h * 336 + 112 + c * 16);
    *(uint4*)(sm + swzaddr(A_KS, m, c * 16, 128)) = kv;
    uint4 vv = *(const uint4*)(qbase + (size_t)m * 2016 + h * 336 + 224 + c * 16);
    union { uint4 q; unsigned short u[8]; } pk; pk.q = vv;
#pragma unroll
    for (int e = 0; e < 8; ++e)
      *(unsigned short*)(sm + swzaddr(A_VT, c * 8 + e, m * 2, 128)) = pk.u[e];
  }
  // stage transposed bias+mask table (already pre-summed, -1e30 pad cols)
  {
    const uint4* src = (const uint4*)(bmallT + (size_t)(wdx * NH + h) * 8192);
    for (int j = tid; j < 512; j += 256) {
      int n = j >> 3, c = j & 7;
      *(uint4*)(sm + swzaddr(A_BMT, n, c * 16, 128)) = src[j];
    }
  }
  const int arow = wv * 16 + l15;
  const int xr = arow < NTOK ? arow : NTOK - 1;
  bf16x8 qa[2];
#pragma unroll
  for (int kt = 0; kt < 2; ++kt)
    qa[kt] = *(const bf16x8*)(qbase + (size_t)xr * 2016 + h * 336 + kt * 64 + l4 * 16);
  __syncthreads();

  // ---- S = (bias+mask) + q k^T  (bm loaded as accumulator init) ----
  f32x4 sv[4];
#pragma unroll
  for (int nt = 0; nt < 4; ++nt) {
    int n = nt * 16 + l15;
#pragma unroll
    for (int r = 0; r < 4; ++r) {
      int m = wv * 16 + l4 * 4 + r;
      int mc = m < NTOK ? m : NTOK - 1;
      sv[nt][r] = __bfloat162float(
          *(const __hip_bfloat16*)(sm + swzaddr(A_BMT, n, mc * 2, 128)));
    }
#pragma unroll
    for (int kt = 0; kt < 2; ++kt) {
      bf16x8 kb = *(const bf16x8*)(sm + swzaddr(A_KS, n, kt * 64 + l4 * 16, 128));
      sv[nt] = __builtin_amdgcn_mfma_f32_16x16x32_bf16(qa[kt], kb, sv[nt], 0, 0, 0);
    }
  }

  // ---- softmax over rows ----
#pragma unroll
  for (int r = 0; r < 4; ++r) {
    float mx = fmaxf(fmaxf(sv[0][r], sv[1][r]), fmaxf(sv[2][r], sv[3][r]));
    mx = fmaxf(mx, __shfl_xor(mx, 1));
    mx = fmaxf(mx, __shfl_xor(mx, 2));
    mx = fmaxf(mx, __shfl_xor(mx, 4));
    mx = fmaxf(mx, __shfl_xor(mx, 8));
    float p0 = __expf(sv[0][r] - mx), p1 = __expf(sv[1][r] - mx);
    float p2 = __expf(sv[2][r] - mx), p3 = __expf(sv[3][r] - mx);
    float sum = p0 + p1 + p2 + p3;
    sum += __shfl_xor(sum, 1);
    sum += __shfl_xor(sum, 2);
    sum += __shfl_xor(sum, 4);
    sum += __shfl_xor(sum, 8);
    float rinv = 1.0f / sum;
    sv[0][r] = p0 * rinv; sv[1][r] = p1 * rinv; sv[2][r] = p2 * rinv; sv[3][r] = p3 * rinv;
  }
  // write P (own rows; same-wave in-order DS, no barrier needed before own reads)
#pragma unroll
  for (int nt = 0; nt < 4; ++nt) {
    int n = nt * 16 + l15;
#pragma unroll
    for (int r = 0; r < 4; ++r) {
      int m = wv * 16 + l4 * 4 + r;
      if (m < NTOK)
        *(__hip_bfloat16*)(sm + swzaddr(A_ATT, m, n * 2, 128)) = __float2bfloat16(sv[nt][r]);
    }
  }

  // ---- O = P @ V ----
  bf16x8 pa[2];
#pragma unroll
  for (int kt = 0; kt < 2; ++kt)
    pa[kt] = *(const bf16x8*)(sm + swzaddr(A_ATT, arow, kt * 64 + l4 * 16, 128));
  f32x4 ov[4];
#pragma unroll
  for (int nt = 0; nt < 4; ++nt) {
    f32x4 a0 = (f32x4){0.f, 0.f, 0.f, 0.f};
#pragma unroll
    for (int kt = 0; kt < 2; ++kt) {
      bf16x8 vb = *(const bf16x8*)(sm + swzaddr(A_VT, nt * 16 + l15, kt * 64 + l4 * 16, 128));
      a0 = __builtin_amdgcn_mfma_f32_16x16x32_bf16(pa[kt], vb, a0, 0, 0, 0);
    }
    ov[nt] = a0;
  }

  // ---- lepe (depthwise 3x3 on v, conflict-free VT reads) ----
  float lep[4][4];
#pragma unroll
  for (int nt = 0; nt < 4; ++nt) {
    int d = nt * 16 + l15;
    if (d < HDIM) {
      const float* lw = lepe_w + (h * HDIM + d) * 9;
      float w9[9];
#pragma unroll
      for (int t9 = 0; t9 < 9; ++t9) w9[t9] = lw[t9];
      float lb = lepe_b[h * HDIM + d];
#pragma unroll
      for (int r = 0; r < 4; ++r) {
        int m = wv * 16 + l4 * 4 + r;
        int y = m / 7, x0 = m - y * 7;
        float lac = lb;
#pragma unroll
        for (int dy = 0; dy < 3; ++dy)
#pragma unroll
          for (int dx = 0; dx < 3; ++dx) {
            int yy = y + dy - 1, xx = x0 + dx - 1;
            if (yy >= 0 && yy < 7 && xx >= 0 && xx < 7) {
              float vvv = __bfloat162float(
                  *(const __hip_bfloat16*)(sm + swzaddr(A_VT, d, (yy * 7 + xx) * 2, 128)));
              lac += w9[dy * 3 + dx] * vvv;
            }
          }
        lep[nt][r] = lac;
      }
    }
  }

  // ---- dump O+lepe into KS region (dead), then coalesced copy into q-slot ----
  __syncthreads();
#pragma unroll
  for (int nt = 0; nt < 4; ++nt) {
    int d = nt * 16 + l15;
    if (d < HDIM) {
#pragma unroll
      for (int r = 0; r < 4; ++r) {
        int m = wv * 16 + l4 * 4 + r;
        if (m < NTOK)
          *(__hip_bfloat16*)(sm + swzaddr(A_KS, m, d * 2, 128)) =
              __float2bfloat16(ov[nt][r] + lep[nt][r]);
      }
    }
  }
  __syncthreads();
  for (int j = tid; j < 343; j += 256) {
    int m = j / 7, c = j - m * 7;
    uint4 v = *(const uint4*)(sm + swzaddr(A_KS, m, c * 16, 128));
    *(uint4*)(qbase + (size_t)m * 2016 + h * 336 + c * 16) = v;
  }
}

// K3: out = O @ projwt2 + b  (M=100352, N=192, K=336->352). A from q-slots (bf16).
// grid (3, 784): consecutive blocks share A rows via L2.
__global__ __launch_bounds__(256, 3) void proj_gemm(
    const float* __restrict__ proj_b, unsigned char* __restrict__ ws,
    float* __restrict__ out) {
  __shared__ uint4 smem4[2816];   // 45056 B: B tile [64][352] bf16 swizzled (stride 704B)
  unsigned char* sm = (unsigned char*)smem4;
  const unsigned char* projwt2 = ws + WS_PROJWT;
  const unsigned char* qkvbuf = ws + WS_QKV;

  const int tid = threadIdx.x;
  const int lane = tid & 63, wv = tid >> 6;
  const int l15 = lane & 15, l4 = lane >> 4;
  const int nbase = blockIdx.x * 64;
  const int mbase = blockIdx.y * 128;

  for (int j = tid; j < 2816; j += 256) {
    int n = j / 44, c = j - n * 44;
    uint4 v = *(const uint4*)(projwt2 + (size_t)(nbase + n) * 704 + c * 16);
    *(uint4*)(sm + swzaddr(0, n, c * 16, 704)) = v;
  }
  f32x4 acc[2][4];
#pragma unroll
  for (int nt = 0; nt < 4; ++nt) {
    float b = proj_b[nbase + nt * 16 + l15];
    acc[0][nt] = (f32x4){b, b, b, b};
    acc[1][nt] = (f32x4){b, b, b, b};
  }
  __syncthreads();

  for (int kt = 0; kt < 11; ++kt) {
    int ks = kt * 32 + l4 * 8;          // kappa slice start (always within one head)
    int hh = ks / 56;
    int rem = ks - hh * 56;
    unsigned aoff = (unsigned)(hh * 336 + rem * 2);
    bf16x8 af[2];
#pragma unroll
    for (int mt = 0; mt < 2; ++mt) {
      int row = mbase + wv * 32 + mt * 16 + l15;
      af[mt] = *(const bf16x8*)(qkvbuf + (size_t)row * 2016 + aoff);
    }
#pragma unroll
    for (int nt = 0; nt < 4; ++nt) {
      bf16x8 pb = *(const bf16x8*)(sm + swzaddr(0, nt * 16 + l15, (kt * 32 + l4 * 8) * 2, 704));
      acc[0][nt] = __builtin_amdgcn_mfma_f32_16x16x32_bf16(af[0], pb, acc[0][nt], 0, 0, 0);
      acc[1][nt] = __builtin_amdgcn_mfma_f32_16x16x32_bf16(af[1], pb, acc[1][nt], 0, 0, 0);
    }
  }
  __syncthreads();

  // dump fp32 C into LDS [128][64] f32 (stride 256B, swizzled), coalesced copy-out
#pragma unroll
  for (int mt = 0; mt < 2; ++mt)
#pragma unroll
    for (int nt = 0; nt < 4; ++nt)
#pragma unroll
      for (int r = 0; r < 4; ++r) {
        int m = wv * 32 + mt * 16 + l4 * 4 + r;
        *(float*)(sm + swzaddr(0, m, (nt * 16 + l15) * 4, 256)) = acc[mt][nt][r];
      }
  __syncthreads();
  for (int j = tid; j < 2048; j += 256) {
    int row = j >> 4, c = j & 15;
    uint4 v = *(const uint4*)(sm + swzaddr(0, row, c * 16, 256));
    *(uint4*)((unsigned char*)out + (size_t)(mbase + row) * 768 + nbase * 4 + c * 16) = v;
  }
}

// ==================== FALLBACK PATH (R2 kernel, verbatim) ====================

__global__ void prep_fb(const float* __restrict__ qkv_w,
                        const float* __restrict__ proj_w,
                        const float* __restrict__ tbl,
                        const int* __restrict__ ridx,
                        unsigned char* __restrict__ ws) {
  __hip_bfloat16* qkvwt  = (__hip_bfloat16*)(ws + FB_QKVWT);
  __hip_bfloat16* projwt = (__hip_bfloat16*)(ws + FB_PROJWT);
  float* bias6 = (float*)(ws + FB_BIAS6);
  int idx = blockIdx.x * 256 + threadIdx.x;
  const int n1 = 1008 * 192;
  const int n2 = 192 * 384;
  const int n3 = 6 * 49 * 49;
  if (idx < n1) {
    int c = idx / 192, k = idx - c * 192;
    qkvwt[idx] = __float2bfloat16(qkv_w[k * 1008 + c]);
  } else if (idx < n1 + n2) {
    int j = idx - n1;
    int c = j / 384, kk = j - c * 384;
    projwt[j] = __float2bfloat16(kk < 336 ? proj_w[kk * 192 + c] : 0.0f);
  } else if (idx < n1 + n2 + n3) {
    int j = idx - n1 - n2;
    int h = j / 2401, mn = j - h * 2401;
    bias6[j] = tbl[ridx[mn] * 6 + h];
  }
}

#define QS_OFF  0
#define KS_OFF  8192
#define VT_OFF  16384
#define ATT_OFF 24576
#define SMEM_BYTES 32768

__global__ __launch_bounds__(256, 4) void winattn_fb(
    const float* __restrict__ x, const float* __restrict__ mask,
    const float* __restrict__ qkv_b, const float* __restrict__ lepe_w,
    const float* __restrict__ lepe_b, const float* __restrict__ proj_b,
    const unsigned char* __restrict__ ws, float* __restrict__ out) {
  __shared__ uint4 smem4[SMEM_BYTES / 16];
  unsigned char* sm = (unsigned char*)smem4;
  const __hip_bfloat16* qkvwt  = (const __hip_bfloat16*)(ws + FB_QKVWT);
  const __hip_bfloat16* projwt = (const __hip_bfloat16*)(ws + FB_PROJWT);
  const float* bias6 = (const float*)(ws + FB_BIAS6);

  const int tid = threadIdx.x;
  const int lane = tid & 63, wv = tid >> 6;
  const int l15 = lane & 15, l4 = lane >> 4;
  const int blk = blockIdx.x;
  const int wdx = blk & 63;
  {
    uint4 z = {0u, 0u, 0u, 0u};
    for (int i = tid; i < SMEM_BYTES / 16; i += 256) smem4[i] = z;
  }
  const int arow = wv * 16 + l15;
  const float* xg = x + (size_t)blk * (NTOK * DIMC);
  const int xr = arow < NTOK ? arow : NTOK - 1;
  bf16x8 afr[6];
#pragma unroll
  for (int kt = 0; kt < 6; ++kt) {
    const float4* p = (const float4*)(xg + xr * DIMC + kt * 32 + l4 * 8);
    float4 a = p[0], b = p[1];
    union { unsigned short u[8]; bf16x8 v; } pk;
    pk.u[0] = f2bu(a.x); pk.u[1] = f2bu(a.y); pk.u[2] = f2bu(a.z); pk.u[3] = f2bu(a.w);
    pk.u[4] = f2bu(b.x); pk.u[5] = f2bu(b.y); pk.u[6] = f2bu(b.z); pk.u[7] = f2bu(b.w);
    afr[kt] = pk.v;
  }
  f32x4 pacc[12];
#pragma unroll
  for (int nt = 0; nt < 12; ++nt) {
    float pb = proj_b[nt * 16 + l15];
    pacc[nt] = (f32x4){pb, pb, pb, pb};
  }
  const float* maskw = mask + wdx * (NTOK * NTOK);
  __syncthreads();

  for (int h = 0; h < NH; ++h) {
    for (int i = tid; i < NTOK * NTOK; i += 256) {
      int row = i / NTOK, col = i - row * NTOK;
      *(unsigned short*)(sm + ATT_OFF + row * 128 + col * 2) =
          f2bu(bias6[h * (NTOK * NTOK) + i] + maskw[i]);
    }
#pragma unroll
    for (int nt = 0; nt < 11; ++nt) {
      int cl = nt * 16 + l15;
      int cg = h * 168 + cl; if (cg > 1007) cg = 1007;
      float bias = qkv_b[cg];
      f32x4 acc = (f32x4){bias, bias, bias, bias};
#pragma unroll
      for (int kt = 0; kt < 6; ++kt) {
        bf16x8 bf = *(const bf16x8*)(qkvwt + cg * DIMC + kt * 32 + l4 * 8);
        acc = __builtin_amdgcn_mfma_f32_16x16x32_bf16(afr[kt], bf, acc, 0, 0, 0);
      }
      if (cl < 168) {
#pragma unroll
        for (int r = 0; r < 4; ++r) {
          int m = wv * 16 + l4 * 4 + r;
          if (m < NTOK) {
            float vv = acc[r];
            if (cl < 56)
              *(__hip_bfloat16*)(sm + swzaddr(QS_OFF, m, cl * 2, 128)) = __float2bfloat16(vv);
            else if (cl < 112)
              *(__hip_bfloat16*)(sm + swzaddr(KS_OFF, m, (cl - 56) * 2, 128)) = __float2bfloat16(vv);
            else
              *(__hip_bfloat16*)(sm + swzaddr(VT_OFF, cl - 112, m * 2, 128)) = __float2bfloat16(vv);
          }
        }
      }
    }
    __syncthreads();
    bf16x8 qa[2];
#pragma unroll
    for (int kt = 0; kt < 2; ++kt)
      qa[kt] = *(const bf16x8*)(sm + swzaddr(QS_OFF, arow, (kt * 32 + l4 * 8) * 2, 128));
    f32x4 sv[4];
#pragma unroll
    for (int nt = 0; nt < 4; ++nt) {
      f32x4 acc = (f32x4){0.f, 0.f, 0.f, 0.f};
#pragma unroll
      for (int kt = 0; kt < 2; ++kt) {
        bf16x8 kb = *(const bf16x8*)(sm + swzaddr(KS_OFF, nt * 16 + l15, (kt * 32 + l4 * 8) * 2, 128));
        acc = __builtin_amdgcn_mfma_f32_16x16x32_bf16(qa[kt], kb, acc, 0, 0, 0);
      }
      sv[nt] = acc;
    }
#pragma unroll
    for (int nt = 0; nt < 4; ++nt) {
      int n = nt * 16 + l15;
#pragma unroll
      for (int r = 0; r < 4; ++r) {
        int m = wv * 16 + l4 * 4 + r;
        int mc = m < NTOK ? m : NTOK - 1;
        float vv;
        if (n < NTOK) {
          float add = __bfloat162float(
              *(const __hip_bfloat16*)(sm + ATT_OFF + mc * 128 + n * 2));
          vv = SCALE * sv[nt][r] + add;
        } else {
          vv = -1e30f;
        }
        sv[nt][r] = vv;
      }
    }
#pragma unroll
    for (int r = 0; r < 4; ++r) {
      float mx = fmaxf(fmaxf(sv[0][r], sv[1][r]), fmaxf(sv[2][r], sv[3][r]));
      mx = fmaxf(mx, __shfl_xor(mx, 1));
      mx = fmaxf(mx, __shfl_xor(mx, 2));
      mx = fmaxf(mx, __shfl_xor(mx, 4));
      mx = fmaxf(mx, __shfl_xor(mx, 8));
      float p0 = __expf(sv[0][r] - mx), p1 = __expf(sv[1][r] - mx);
      float p2 = __expf(sv[2][r] - mx), p3 = __expf(sv[3][r] - mx);
      float sum = p0 + p1 + p2 + p3;
      sum += __shfl_xor(sum, 1);
      sum += __shfl_xor(sum, 2);
      sum += __shfl_xor(sum, 4);
      sum += __shfl_xor(sum, 8);
      float rinv = 1.0f / sum;
      sv[0][r] = p0 * rinv; sv[1][r] = p1 * rinv; sv[2][r] = p2 * rinv; sv[3][r] = p3 * rinv;
    }
#pragma unroll
    for (int nt = 0; nt < 4; ++nt) {
      int n = nt * 16 + l15;
#pragma unroll
      for (int r = 0; r < 4; ++r) {
        int m = wv * 16 + l4 * 4 + r;
        if (m < NTOK)
          *(__hip_bfloat16*)(sm + swzaddr(ATT_OFF, m, n * 2, 128)) = __float2bfloat16(sv[nt][r]);
      }
    }
    bf16x8 pa[2];
#pragma unroll
    for (int kt = 0; kt < 2; ++kt)
      pa[kt] = *(const bf16x8*)(sm + swzaddr(ATT_OFF, arow, (kt * 32 + l4 * 8) * 2, 128));
    f32x4 ov[4];
#pragma unroll
    for (int nt = 0; nt < 4; ++nt) {
      f32x4 acc = (f32x4){0.f, 0.f, 0.f, 0.f};
#pragma unroll
      for (int kt = 0; kt < 2; ++kt) {
        bf16x8 vb = *(const bf16x8*)(sm + swzaddr(VT_OFF, nt * 16 + l15, (kt * 32 + l4 * 8) * 2, 128));
        acc = __builtin_amdgcn_mfma_f32_16x16x32_bf16(pa[kt], vb, acc, 0, 0, 0);
      }
      ov[nt] = acc;
    }
#pragma unroll
    for (int nt = 0; nt < 4; ++nt) {
      int d = nt * 16 + l15;
      if (d < HDIM) {
        const float* lw = lepe_w + (h * HDIM + d) * 9;
        float w9[9];
#pragma unroll
        for (int t9 = 0; t9 < 9; ++t9) w9[t9] = lw[t9];
        float lb = lepe_b[h * HDIM + d];
#pragma unroll
        for (int r = 0; r < 4; ++r) {
          int m = wv * 16 + l4 * 4 + r;
          if (m < NTOK) {
            int y = m / 7, x0 = m - y * 7;
            float lac = lb;
#pragma unroll
            for (int dy = 0; dy < 3; ++dy)
#pragma unroll
              for (int dx = 0; dx < 3; ++dx) {
                int yy = y + dy - 1, xx = x0 + dx - 1;
                if (yy >= 0 && yy < 7 && xx >= 0 && xx < 7) {
                  float vvv = __bfloat162float(
                      *(const __hip_bfloat16*)(sm + swzaddr(VT_OFF, d, (yy * 7 + xx) * 2, 128)));
                  lac += w9[dy * 3 + dx] * vvv;
                }
              }
            *(__hip_bfloat16*)(sm + swzaddr(QS_OFF, m, d * 2, 128)) =
                __float2bfloat16(ov[nt][r] + lac);
          }
        }
      }
    }
    bf16x8 oa[2];
#pragma unroll
    for (int kt = 0; kt < 2; ++kt)
      oa[kt] = *(const bf16x8*)(sm + swzaddr(QS_OFF, arow, (kt * 32 + l4 * 8) * 2, 128));
#pragma unroll
    for (int nt = 0; nt < 12; ++nt) {
#pragma unroll
      for (int kt = 0; kt < 2; ++kt) {
        bf16x8 pb = *(const bf16x8*)(projwt + (nt * 16 + l15) * 384 + h * HDIM + kt * 32 + l4 * 8);
        pacc[nt] = __builtin_amdgcn_mfma_f32_16x16x32_bf16(oa[kt], pb, pacc[nt], 0, 0, 0);
      }
    }
    __syncthreads();
  }
  float* og = out + (size_t)blk * (NTOK * DIMC);
#pragma unroll
  for (int nt = 0; nt < 12; ++nt) {
#pragma unroll
    for (int r = 0; r < 4; ++r) {
      int m = wv * 16 + l4 * 4 + r;
      if (m < NTOK) og[m * DIMC + nt * 16 + l15] = pacc[nt][r];
    }
  }
}

// ==================== launcher ====================

extern "C" void kernel_launch(void* const* d_in, const int* in_sizes, int n_in,
                              void* d_out, int out_size, void* d_ws, size_t ws_size,
                              hipStream_t stream) {
  const float* x      = (const float*)d_in[0];
  const float* mask   = (const float*)d_in[1];
  const float* qkv_w  = (const float*)d_in[2];
  const float* qkv_b  = (const float*)d_in[3];
  const float* tbl    = (const float*)d_in[4];
  const int*   ridx   = (const int*)d_in[5];
  const float* lepe_w = (const float*)d_in[6];
  const float* lepe_b = (const float*)d_in[7];
  const float* proj_w = (const float*)d_in[8];
  const float* proj_b = (const float*)d_in[9];
  unsigned char* ws = (unsigned char*)d_ws;
  float* out = (float*)d_out;

  if (ws_size >= WS_NEED) {
    const int n_prep = 1008 * 192 + 192 * 352 + 1008 + 64 * 6 * 64 * 64;
    prep_main<<<dim3((n_prep + 255) / 256), dim3(256), 0, stream>>>(
        qkv_w, qkv_b, proj_w, tbl, ridx, mask, ws);
    qkv_gemm<<<dim3(7, 784), dim3(256), 0, stream>>>(x, ws);
    attn_head<<<dim3(6, 2048), dim3(256), 0, stream>>>(lepe_w, lepe_b, ws);
    proj_gemm<<<dim3(3, 784), dim3(256), 0, stream>>>(proj_b, ws, out);
  } else {
    prep_fb<<<dim3(1101), dim3(256), 0, stream>>>(qkv_w, proj_w, tbl, ridx, ws);
    winattn_fb<<<dim3(2048), dim3(256), 0, stream>>>(x, mask, qkv_b, lepe_w, lepe_b,
                                                     proj_b, ws, out);
  }
}

// Round 6
// 382.307 us; speedup vs baseline: 4.5622x; 1.1480x over previous
//
#include <hip/hip_runtime.h>
#include <hip/hip_bf16.h>

typedef __bf16 bf16x8 __attribute__((ext_vector_type(8)));
typedef unsigned short u16x8 __attribute__((ext_vector_type(8)));
typedef float f32x4 __attribute__((ext_vector_type(4)));

#define NTOK 49
#define NH   6
#define HDIM 56
#define DIMC 192
#define SCALE 0.17677669529663687f

// ---------------- workspace layout (bytes) ----------------
#define WS_QKVWT   0u          // bf16 [1008][192] transposed qkv_w, q-cols pre-scaled
#define WS_PROJWT  387072u     // bf16 [192][352]  transposed proj_w, K padded 336->352 w/ zeros
#define WS_QKVBS   522240u     // f32  [1008]      qkv_b, q-entries pre-scaled
#define WS_BMALLT  526272u     // bf16 [64][6][64 n][64 m] transposed bias+mask
#define WS_LEPET   3672000u    // f32  [9][336]    lepe_w transposed (tap-major)
#define WS_QKV     3684288u    // bf16 [100352][1008] qkv activations (q-slot later holds O+lepe)
#define WS_NEED    (WS_QKV + (size_t)100352 * 2016 + 4096)
// fallback path (R2 layout, 591KB):
#define FB_QKVWT  0
#define FB_PROJWT 387072
#define FB_BIAS6  534528

__device__ __forceinline__ unsigned swzaddr(unsigned base, int row, int colb, int strideb) {
  return base + (unsigned)((row * strideb + colb) ^ ((row & 7) << 4));
}

__device__ __forceinline__ unsigned short f2bu(float f) {
  __hip_bfloat16 h = __float2bfloat16(f);
  unsigned short u;
  __builtin_memcpy(&u, &h, 2);
  return u;
}

__device__ __forceinline__ float bu2f(unsigned short u) {
  union { unsigned int i; float f; } x;
  x.i = ((unsigned int)u) << 16;
  return x.f;
}

// ==================== MAIN PATH ====================

__global__ void prep_main(const float* __restrict__ qkv_w,
                          const float* __restrict__ qkv_b,
                          const float* __restrict__ proj_w,
                          const float* __restrict__ tbl,
                          const int* __restrict__ ridx,
                          const float* __restrict__ mask,
                          const float* __restrict__ lepe_w,
                          unsigned char* __restrict__ ws) {
  __hip_bfloat16* qkvwt   = (__hip_bfloat16*)(ws + WS_QKVWT);
  __hip_bfloat16* projwt2 = (__hip_bfloat16*)(ws + WS_PROJWT);
  float*          qkvbs   = (float*)(ws + WS_QKVBS);
  __hip_bfloat16* bmallT  = (__hip_bfloat16*)(ws + WS_BMALLT);
  float*          lepeT   = (float*)(ws + WS_LEPET);
  int idx = blockIdx.x * 256 + threadIdx.x;
  const int n1 = 1008 * 192;        // qkvwt
  const int n2 = 192 * 352;         // projwt2
  const int n3 = 1008;              // qkvbs
  const int n4 = 64 * 6 * 64 * 64;  // bmallT
  const int n5 = 9 * 336;           // lepeT
  if (idx < n1) {
    int c = idx / 192, k = idx - c * 192;
    float v = qkv_w[k * 1008 + c];
    if (c % 168 < 56) v *= SCALE;
    qkvwt[idx] = __float2bfloat16(v);
  } else if (idx < n1 + n2) {
    int j = idx - n1;
    int n = j / 352, kk = j - n * 352;
    projwt2[j] = __float2bfloat16(kk < 336 ? proj_w[kk * 192 + n] : 0.0f);
  } else if (idx < n1 + n2 + n3) {
    int c = idx - n1 - n2;
    float v = qkv_b[c];
    if (c % 168 < 56) v *= SCALE;
    qkvbs[c] = v;
  } else if (idx < n1 + n2 + n3 + n4) {
    int j = idx - n1 - n2 - n3;
    int wh = j >> 12;
    int e = j & 4095;
    int n = e >> 6, m = e & 63;
    int wdx = wh / 6, h = wh - wdx * 6;
    float v;
    if (n >= NTOK) v = -1e30f;
    else if (m >= NTOK) v = 0.0f;
    else v = tbl[ridx[m * NTOK + n] * NH + h] + mask[wdx * (NTOK * NTOK) + m * NTOK + n];
    bmallT[j] = __float2bfloat16(v);
  } else if (idx < n1 + n2 + n3 + n4 + n5) {
    int j = idx - n1 - n2 - n3 - n4;
    int tap = j / 336, hd = j - tap * 336;
    lepeT[j] = lepe_w[hd * 9 + tap];
  }
}

// K1: qkv = x @ Wqkv + b  (M=100352, N=1008, K=192), bf16 out.
__global__ __launch_bounds__(256, 2) void qkv_gemm(
    const float* __restrict__ x, unsigned char* __restrict__ ws) {
  __shared__ uint4 smem4[3456];   // 55296 B: B tile [144][192] bf16 swizzled (stride 384B)
  unsigned char* sm = (unsigned char*)smem4;
  const __hip_bfloat16* qkvwt = (const __hip_bfloat16*)(ws + WS_QKVWT);
  const float* qkvbs = (const float*)(ws + WS_QKVBS);
  unsigned char* qkvbuf = ws + WS_QKV;

  const int tid = threadIdx.x;
  const int lane = tid & 63, wv = tid >> 6;
  const int l15 = lane & 15, l4 = lane >> 4;
  const int nbase = blockIdx.x * 144;
  const int mbase = blockIdx.y * 128;

  {
    const uint4* bsrc = (const uint4*)(qkvwt + nbase * 192);
    for (int j = tid; j < 3456; j += 256) {
      int row = j / 24, c16 = j - row * 24;
      *(uint4*)(sm + swzaddr(0, row, c16 * 16, 384)) = bsrc[j];
    }
  }

  bf16x8 afr[2][6];
#pragma unroll
  for (int mt = 0; mt < 2; ++mt) {
    int g = mbase + wv * 32 + mt * 16 + l15;
    const float* xr = x + (size_t)g * DIMC;
#pragma unroll
    for (int kt = 0; kt < 6; ++kt) {
      const float4* p = (const float4*)(xr + kt * 32 + l4 * 8);
      float4 a = p[0], b = p[1];
      union { unsigned short u[8]; bf16x8 v; } pk;
      pk.u[0] = f2bu(a.x); pk.u[1] = f2bu(a.y); pk.u[2] = f2bu(a.z); pk.u[3] = f2bu(a.w);
      pk.u[4] = f2bu(b.x); pk.u[5] = f2bu(b.y); pk.u[6] = f2bu(b.z); pk.u[7] = f2bu(b.w);
      afr[mt][kt] = pk.v;
    }
  }

  f32x4 acc[2][9];
#pragma unroll
  for (int nt = 0; nt < 9; ++nt) {
    float b = qkvbs[nbase + nt * 16 + l15];
    acc[0][nt] = (f32x4){b, b, b, b};
    acc[1][nt] = (f32x4){b, b, b, b};
  }
  __syncthreads();

#pragma unroll
  for (int kt = 0; kt < 6; ++kt) {
#pragma unroll
    for (int nt = 0; nt < 9; ++nt) {
      bf16x8 bf = *(const bf16x8*)(sm + swzaddr(0, nt * 16 + l15, kt * 64 + l4 * 16, 384));
      acc[0][nt] = __builtin_amdgcn_mfma_f32_16x16x32_bf16(afr[0][kt], bf, acc[0][nt], 0, 0, 0);
      acc[1][nt] = __builtin_amdgcn_mfma_f32_16x16x32_bf16(afr[1][kt], bf, acc[1][nt], 0, 0, 0);
    }
  }
  __syncthreads();

#pragma unroll
  for (int mt = 0; mt < 2; ++mt)
#pragma unroll
    for (int nt = 0; nt < 9; ++nt)
#pragma unroll
      for (int r = 0; r < 4; ++r) {
        int row = wv * 32 + mt * 16 + l4 * 4 + r;
        *(unsigned short*)(sm + swzaddr(0, row, (nt * 16 + l15) * 2, 384)) =
            f2bu(acc[mt][nt][r]);
      }
  __syncthreads();
  for (int j = tid; j < 2304; j += 256) {
    int row = j / 18, c16 = j - row * 18;
    uint4 v = *(const uint4*)(sm + swzaddr(0, row, c16 * 16, 384));
    *(uint4*)(qkvbuf + (size_t)(mbase + row) * 2016 + nbase * 2 + c16 * 16) = v;
  }
}

// K2: one block per (head, window).
// LDS: KS 8K | VT 8K | BMT 8K | ATT 8K | VS 8K = 40K. OS (f32 [64][64], stride 256B)
// overlays KS+VT after PV.
#define A_KS   0u
#define A_VT   8192u
#define A_BMT  16384u
#define A_ATT  24576u
#define A_VS   32768u
#define A_SMEM 40960u

__global__ __launch_bounds__(256, 4) void attn_head(
    const float* __restrict__ lepe_b, unsigned char* __restrict__ ws) {
  __shared__ uint4 smem4[A_SMEM / 16];
  unsigned char* sm = (unsigned char*)smem4;
  const unsigned char* bmallT = ws + WS_BMALLT;
  const float* lepeT = (const float*)(ws + WS_LEPET);
  unsigned char* qkvbuf = ws + WS_QKV;

  const int tid = threadIdx.x;
  const int lane = tid & 63, wv = tid >> 6;
  const int l15 = lane & 15, l4 = lane >> 4;
  const int h = blockIdx.x;
  const int win = blockIdx.y;
  const int wdx = win & 63;
  unsigned char* qbase = qkvbuf + (size_t)win * (NTOK * 2016);

  // zero KS+VT only (16KB): their pads feed MFMA B-operands and must be exact 0.
  {
    uint4 z = {0u, 0u, 0u, 0u};
    for (int i = tid; i < 1024; i += 256) smem4[i] = z;
  }
  __syncthreads();

  // stage k (KS), v row-major (VS), v transposed (VT). m-major lane map: the 8
  // scalar VT stores then span 49 distinct m -> ~25 banks (2-way, free).
  for (int j = tid; j < 343; j += 256) {
    int m = j % 49, c = j / 49;
    const unsigned char* row = qbase + (size_t)m * 2016 + h * 336;
    uint4 kv = *(const uint4*)(row + 112 + c * 16);
    *(uint4*)(sm + swzaddr(A_KS, m, c * 16, 128)) = kv;
    uint4 vv = *(const uint4*)(row + 224 + c * 16);
    *(uint4*)(sm + swzaddr(A_VS, m, c * 16, 128)) = vv;
    union { uint4 q; unsigned short u[8]; } pk; pk.q = vv;
#pragma unroll
    for (int e = 0; e < 8; ++e)
      *(unsigned short*)(sm + swzaddr(A_VT, c * 8 + e, m * 2, 128)) = pk.u[e];
  }
  // stage transposed bias+mask table (pre-summed, -1e30 pad cols)
  {
    const uint4* src = (const uint4*)(bmallT + (size_t)(wdx * NH + h) * 8192);
    for (int j = tid; j < 512; j += 256) {
      int n = j >> 3, c = j & 7;
      *(uint4*)(sm + swzaddr(A_BMT, n, c * 16, 128)) = src[j];
    }
  }
  const int arow = wv * 16 + l15;
  const int xr = arow < NTOK ? arow : NTOK - 1;
  bf16x8 qa[2];
#pragma unroll
  for (int kt = 0; kt < 2; ++kt)
    qa[kt] = *(const bf16x8*)(qbase + (size_t)xr * 2016 + h * 336 + kt * 64 + l4 * 16);
  __syncthreads();

  // ---- S = (bias+mask) + q k^T  (bm loaded via one ds_read_b64 per n-tile) ----
  const int mc0 = wv * 16 + l4 * 4;
  f32x4 sv[4];
#pragma unroll
  for (int nt = 0; nt < 4; ++nt) {
    int n = nt * 16 + l15;
    unsigned long long bm8 =
        *(const unsigned long long*)(sm + swzaddr(A_BMT, n, mc0 * 2, 128));
#pragma unroll
    for (int r = 0; r < 4; ++r)
      sv[nt][r] = bu2f((unsigned short)(bm8 >> (16 * r)));
#pragma unroll
    for (int kt = 0; kt < 2; ++kt) {
      bf16x8 kb = *(const bf16x8*)(sm + swzaddr(A_KS, n, kt * 64 + l4 * 16, 128));
      sv[nt] = __builtin_amdgcn_mfma_f32_16x16x32_bf16(qa[kt], kb, sv[nt], 0, 0, 0);
    }
  }

  // ---- softmax over rows ----
#pragma unroll
  for (int r = 0; r < 4; ++r) {
    float mx = fmaxf(fmaxf(sv[0][r], sv[1][r]), fmaxf(sv[2][r], sv[3][r]));
    mx = fmaxf(mx, __shfl_xor(mx, 1));
    mx = fmaxf(mx, __shfl_xor(mx, 2));
    mx = fmaxf(mx, __shfl_xor(mx, 4));
    mx = fmaxf(mx, __shfl_xor(mx, 8));
    float p0 = __expf(sv[0][r] - mx), p1 = __expf(sv[1][r] - mx);
    float p2 = __expf(sv[2][r] - mx), p3 = __expf(sv[3][r] - mx);
    float sum = p0 + p1 + p2 + p3;
    sum += __shfl_xor(sum, 1);
    sum += __shfl_xor(sum, 2);
    sum += __shfl_xor(sum, 4);
    sum += __shfl_xor(sum, 8);
    float rinv = 1.0f / sum;
    sv[0][r] = p0 * rinv; sv[1][r] = p1 * rinv; sv[2][r] = p2 * rinv; sv[3][r] = p3 * rinv;
  }
  // write P (own rows; same-wave in-order DS)
#pragma unroll
  for (int nt = 0; nt < 4; ++nt) {
    int n = nt * 16 + l15;
#pragma unroll
    for (int r = 0; r < 4; ++r) {
      int m = mc0 + r;
      if (m < NTOK)
        *(__hip_bfloat16*)(sm + swzaddr(A_ATT, m, n * 2, 128)) = __float2bfloat16(sv[nt][r]);
    }
  }

  // ---- O = P @ V ----
  bf16x8 pa[2];
#pragma unroll
  for (int kt = 0; kt < 2; ++kt)
    pa[kt] = *(const bf16x8*)(sm + swzaddr(A_ATT, arow, kt * 64 + l4 * 16, 128));
  f32x4 ov[4];
#pragma unroll
  for (int nt = 0; nt < 4; ++nt) {
    f32x4 a0 = (f32x4){0.f, 0.f, 0.f, 0.f};
#pragma unroll
    for (int kt = 0; kt < 2; ++kt) {
      bf16x8 vb = *(const bf16x8*)(sm + swzaddr(A_VT, nt * 16 + l15, kt * 64 + l4 * 16, 128));
      a0 = __builtin_amdgcn_mfma_f32_16x16x32_bf16(pa[kt], vb, a0, 0, 0, 0);
    }
    ov[nt] = a0;
  }

  // ---- dump O (f32) into OS = KS+VT region (dead after PV) ----
  __syncthreads();
#pragma unroll
  for (int nt = 0; nt < 4; ++nt) {
    int d = nt * 16 + l15;
#pragma unroll
    for (int r = 0; r < 4; ++r) {
      int m = mc0 + r;
      *(float*)(sm + swzaddr(0, m, d * 4, 256)) = ov[nt][r];
    }
  }
  __syncthreads();

  // ---- fused: out[m][d0..d0+7] = O + lepe, write straight to q-slot ----
  for (int j = tid; j < 343; j += 256) {
    int m = j % 49, c = j / 49;
    int y = m / 7, x0 = m - y * 7;
    float4 o0 = *(const float4*)(sm + swzaddr(0, m, c * 32, 256));
    float4 o1 = *(const float4*)(sm + swzaddr(0, m, c * 32 + 16, 256));
    const float4* lb = (const float4*)(lepe_b + h * HDIM + c * 8);
    float4 b0 = lb[0], b1 = lb[1];
    float4 a0, a1;
    a0.x = o0.x + b0.x; a0.y = o0.y + b0.y; a0.z = o0.z + b0.z; a0.w = o0.w + b0.w;
    a1.x = o1.x + b1.x; a1.y = o1.y + b1.y; a1.z = o1.z + b1.z; a1.w = o1.w + b1.w;
#pragma unroll
    for (int dy = 0; dy < 3; ++dy) {
      int yy = y + dy - 1;
      if (yy < 0 || yy >= 7) continue;
#pragma unroll
      for (int dx = 0; dx < 3; ++dx) {
        int xx = x0 + dx - 1;
        if (xx < 0 || xx >= 7) continue;
        int mp = yy * 7 + xx;
        u16x8 vsv = *(const u16x8*)(sm + swzaddr(A_VS, mp, c * 16, 128));
        const float4* wr = (const float4*)(lepeT + (dy * 3 + dx) * 336 + h * HDIM + c * 8);
        float4 w0 = wr[0], w1 = wr[1];
        a0.x += w0.x * bu2f(vsv[0]); a0.y += w0.y * bu2f(vsv[1]);
        a0.z += w0.z * bu2f(vsv[2]); a0.w += w0.w * bu2f(vsv[3]);
        a1.x += w1.x * bu2f(vsv[4]); a1.y += w1.y * bu2f(vsv[5]);
        a1.z += w1.z * bu2f(vsv[6]); a1.w += w1.w * bu2f(vsv[7]);
      }
    }
    union { unsigned short u[8]; uint4 q; } st;
    st.u[0] = f2bu(a0.x); st.u[1] = f2bu(a0.y); st.u[2] = f2bu(a0.z); st.u[3] = f2bu(a0.w);
    st.u[4] = f2bu(a1.x); st.u[5] = f2bu(a1.y); st.u[6] = f2bu(a1.z); st.u[7] = f2bu(a1.w);
    *(uint4*)(qbase + (size_t)m * 2016 + h * 336 + c * 16) = st.q;
  }
}

// K3: out = O @ projwt2 + b  (M=100352, N=192, K=336->352). A from q-slots (bf16).
__global__ __launch_bounds__(256, 3) void proj_gemm(
    const float* __restrict__ proj_b, unsigned char* __restrict__ ws,
    float* __restrict__ out) {
  __shared__ uint4 smem4[2816];   // 45056 B: B tile [64][352] bf16 swizzled (stride 704B)
  unsigned char* sm = (unsigned char*)smem4;
  const unsigned char* projwt2 = ws + WS_PROJWT;
  const unsigned char* qkvbuf = ws + WS_QKV;

  const int tid = threadIdx.x;
  const int lane = tid & 63, wv = tid >> 6;
  const int l15 = lane & 15, l4 = lane >> 4;
  const int nbase = blockIdx.x * 64;
  const int mbase = blockIdx.y * 128;

  for (int j = tid; j < 2816; j += 256) {
    int n = j / 44, c = j - n * 44;
    uint4 v = *(const uint4*)(projwt2 + (size_t)(nbase + n) * 704 + c * 16);
    *(uint4*)(sm + swzaddr(0, n, c * 16, 704)) = v;
  }
  f32x4 acc[2][4];
#pragma unroll
  for (int nt = 0; nt < 4; ++nt) {
    float b = proj_b[nbase + nt * 16 + l15];
    acc[0][nt] = (f32x4){b, b, b, b};
    acc[1][nt] = (f32x4){b, b, b, b};
  }
  __syncthreads();

  for (int kt = 0; kt < 11; ++kt) {
    int ks = kt * 32 + l4 * 8;
    int hh = ks / 56;
    int rem = ks - hh * 56;
    unsigned aoff = (unsigned)(hh * 336 + rem * 2);
    bf16x8 af[2];
#pragma unroll
    for (int mt = 0; mt < 2; ++mt) {
      int row = mbase + wv * 32 + mt * 16 + l15;
      af[mt] = *(const bf16x8*)(qkvbuf + (size_t)row * 2016 + aoff);
    }
#pragma unroll
    for (int nt = 0; nt < 4; ++nt) {
      bf16x8 pb = *(const bf16x8*)(sm + swzaddr(0, nt * 16 + l15, (kt * 32 + l4 * 8) * 2, 704));
      acc[0][nt] = __builtin_amdgcn_mfma_f32_16x16x32_bf16(af[0], pb, acc[0][nt], 0, 0, 0);
      acc[1][nt] = __builtin_amdgcn_mfma_f32_16x16x32_bf16(af[1], pb, acc[1][nt], 0, 0, 0);
    }
  }
  __syncthreads();

#pragma unroll
  for (int mt = 0; mt < 2; ++mt)
#pragma unroll
    for (int nt = 0; nt < 4; ++nt)
#pragma unroll
      for (int r = 0; r < 4; ++r) {
        int m = wv * 32 + mt * 16 + l4 * 4 + r;
        *(float*)(sm + swzaddr(0, m, (nt * 16 + l15) * 4, 256)) = acc[mt][nt][r];
      }
  __syncthreads();
  for (int j = tid; j < 2048; j += 256) {
    int row = j >> 4, c = j & 15;
    uint4 v = *(const uint4*)(sm + swzaddr(0, row, c * 16, 256));
    *(uint4*)((unsigned char*)out + (size_t)(mbase + row) * 768 + nbase * 4 + c * 16) = v;
  }
}

// ==================== FALLBACK PATH (R2 kernel, verbatim) ====================

__global__ void prep_fb(const float* __restrict__ qkv_w,
                        const float* __restrict__ proj_w,
                        const float* __restrict__ tbl,
                        const int* __restrict__ ridx,
                        unsigned char* __restrict__ ws) {
  __hip_bfloat16* qkvwt  = (__hip_bfloat16*)(ws + FB_QKVWT);
  __hip_bfloat16* projwt = (__hip_bfloat16*)(ws + FB_PROJWT);
  float* bias6 = (float*)(ws + FB_BIAS6);
  int idx = blockIdx.x * 256 + threadIdx.x;
  const int n1 = 1008 * 192;
  const int n2 = 192 * 384;
  const int n3 = 6 * 49 * 49;
  if (idx < n1) {
    int c = idx / 192, k = idx - c * 192;
    qkvwt[idx] = __float2bfloat16(qkv_w[k * 1008 + c]);
  } else if (idx < n1 + n2) {
    int j = idx - n1;
    int c = j / 384, kk = j - c * 384;
    projwt[j] = __float2bfloat16(kk < 336 ? proj_w[kk * 192 + c] : 0.0f);
  } else if (idx < n1 + n2 + n3) {
    int j = idx - n1 - n2;
    int h = j / 2401, mn = j - h * 2401;
    bias6[j] = tbl[ridx[mn] * 6 + h];
  }
}

#define QS_OFF  0
#define KS_OFF  8192
#define VT_OFF  16384
#define ATT_OFF 24576
#define SMEM_BYTES 32768

__global__ __launch_bounds__(256, 4) void winattn_fb(
    const float* __restrict__ x, const float* __restrict__ mask,
    const float* __restrict__ qkv_b, const float* __restrict__ lepe_w,
    const float* __restrict__ lepe_b, const float* __restrict__ proj_b,
    const unsigned char* __restrict__ ws, float* __restrict__ out) {
  __shared__ uint4 smem4[SMEM_BYTES / 16];
  unsigned char* sm = (unsigned char*)smem4;
  const __hip_bfloat16* qkvwt  = (const __hip_bfloat16*)(ws + FB_QKVWT);
  const __hip_bfloat16* projwt = (const __hip_bfloat16*)(ws + FB_PROJWT);
  const float* bias6 = (const float*)(ws + FB_BIAS6);

  const int tid = threadIdx.x;
  const int lane = tid & 63, wv = tid >> 6;
  const int l15 = lane & 15, l4 = lane >> 4;
  const int blk = blockIdx.x;
  const int wdx = blk & 63;
  {
    uint4 z = {0u, 0u, 0u, 0u};
    for (int i = tid; i < SMEM_BYTES / 16; i += 256) smem4[i] = z;
  }
  const int arow = wv * 16 + l15;
  const float* xg = x + (size_t)blk * (NTOK * DIMC);
  const int xr = arow < NTOK ? arow : NTOK - 1;
  bf16x8 afr[6];
#pragma unroll
  for (int kt = 0; kt < 6; ++kt) {
    const float4* p = (const float4*)(xg + xr * DIMC + kt * 32 + l4 * 8);
    float4 a = p[0], b = p[1];
    union { unsigned short u[8]; bf16x8 v; } pk;
    pk.u[0] = f2bu(a.x); pk.u[1] = f2bu(a.y); pk.u[2] = f2bu(a.z); pk.u[3] = f2bu(a.w);
    pk.u[4] = f2bu(b.x); pk.u[5] = f2bu(b.y); pk.u[6] = f2bu(b.z); pk.u[7] = f2bu(b.w);
    afr[kt] = pk.v;
  }
  f32x4 pacc[12];
#pragma unroll
  for (int nt = 0; nt < 12; ++nt) {
    float pb = proj_b[nt * 16 + l15];
    pacc[nt] = (f32x4){pb, pb, pb, pb};
  }
  const float* maskw = mask + wdx * (NTOK * NTOK);
  __syncthreads();

  for (int h = 0; h < NH; ++h) {
    for (int i = tid; i < NTOK * NTOK; i += 256) {
      int row = i / NTOK, col = i - row * NTOK;
      *(unsigned short*)(sm + ATT_OFF + row * 128 + col * 2) =
          f2bu(bias6[h * (NTOK * NTOK) + i] + maskw[i]);
    }
#pragma unroll
    for (int nt = 0; nt < 11; ++nt) {
      int cl = nt * 16 + l15;
      int cg = h * 168 + cl; if (cg > 1007) cg = 1007;
      float bias = qkv_b[cg];
      f32x4 acc = (f32x4){bias, bias, bias, bias};
#pragma unroll
      for (int kt = 0; kt < 6; ++kt) {
        bf16x8 bf = *(const bf16x8*)(qkvwt + cg * DIMC + kt * 32 + l4 * 8);
        acc = __builtin_amdgcn_mfma_f32_16x16x32_bf16(afr[kt], bf, acc, 0, 0, 0);
      }
      if (cl < 168) {
#pragma unroll
        for (int r = 0; r < 4; ++r) {
          int m = wv * 16 + l4 * 4 + r;
          if (m < NTOK) {
            float vv = acc[r];
            if (cl < 56)
              *(__hip_bfloat16*)(sm + swzaddr(QS_OFF, m, cl * 2, 128)) = __float2bfloat16(vv);
            else if (cl < 112)
              *(__hip_bfloat16*)(sm + swzaddr(KS_OFF, m, (cl - 56) * 2, 128)) = __float2bfloat16(vv);
            else
              *(__hip_bfloat16*)(sm + swzaddr(VT_OFF, cl - 112, m * 2, 128)) = __float2bfloat16(vv);
          }
        }
      }
    }
    __syncthreads();
    bf16x8 qa[2];
#pragma unroll
    for (int kt = 0; kt < 2; ++kt)
      qa[kt] = *(const bf16x8*)(sm + swzaddr(QS_OFF, arow, (kt * 32 + l4 * 8) * 2, 128));
    f32x4 sv[4];
#pragma unroll
    for (int nt = 0; nt < 4; ++nt) {
      f32x4 acc = (f32x4){0.f, 0.f, 0.f, 0.f};
#pragma unroll
      for (int kt = 0; kt < 2; ++kt) {
        bf16x8 kb = *(const bf16x8*)(sm + swzaddr(KS_OFF, nt * 16 + l15, (kt * 32 + l4 * 8) * 2, 128));
        acc = __builtin_amdgcn_mfma_f32_16x16x32_bf16(qa[kt], kb, acc, 0, 0, 0);
      }
      sv[nt] = acc;
    }
#pragma unroll
    for (int nt = 0; nt < 4; ++nt) {
      int n = nt * 16 + l15;
#pragma unroll
      for (int r = 0; r < 4; ++r) {
        int m = wv * 16 + l4 * 4 + r;
        int mc = m < NTOK ? m : NTOK - 1;
        float vv;
        if (n < NTOK) {
          float add = __bfloat162float(
              *(const __hip_bfloat16*)(sm + ATT_OFF + mc * 128 + n * 2));
          vv = SCALE * sv[nt][r] + add;
        } else {
          vv = -1e30f;
        }
        sv[nt][r] = vv;
      }
    }
#pragma unroll
    for (int r = 0; r < 4; ++r) {
      float mx = fmaxf(fmaxf(sv[0][r], sv[1][r]), fmaxf(sv[2][r], sv[3][r]));
      mx = fmaxf(mx, __shfl_xor(mx, 1));
      mx = fmaxf(mx, __shfl_xor(mx, 2));
      mx = fmaxf(mx, __shfl_xor(mx, 4));
      mx = fmaxf(mx, __shfl_xor(mx, 8));
      float p0 = __expf(sv[0][r] - mx), p1 = __expf(sv[1][r] - mx);
      float p2 = __expf(sv[2][r] - mx), p3 = __expf(sv[3][r] - mx);
      float sum = p0 + p1 + p2 + p3;
      sum += __shfl_xor(sum, 1);
      sum += __shfl_xor(sum, 2);
      sum += __shfl_xor(sum, 4);
      sum += __shfl_xor(sum, 8);
      float rinv = 1.0f / sum;
      sv[0][r] = p0 * rinv; sv[1][r] = p1 * rinv; sv[2][r] = p2 * rinv; sv[3][r] = p3 * rinv;
    }
#pragma unroll
    for (int nt = 0; nt < 4; ++nt) {
      int n = nt * 16 + l15;
#pragma unroll
      for (int r = 0; r < 4; ++r) {
        int m = wv * 16 + l4 * 4 + r;
        if (m < NTOK)
          *(__hip_bfloat16*)(sm + swzaddr(ATT_OFF, m, n * 2, 128)) = __float2bfloat16(sv[nt][r]);
      }
    }
    bf16x8 pa[2];
#pragma unroll
    for (int kt = 0; kt < 2; ++kt)
      pa[kt] = *(const bf16x8*)(sm + swzaddr(ATT_OFF, arow, (kt * 32 + l4 * 8) * 2, 128));
    f32x4 ov[4];
#pragma unroll
    for (int nt = 0; nt < 4; ++nt) {
      f32x4 acc = (f32x4){0.f, 0.f, 0.f, 0.f};
#pragma unroll
      for (int kt = 0; kt < 2; ++kt) {
        bf16x8 vb = *(const bf16x8*)(sm + swzaddr(VT_OFF, nt * 16 + l15, (kt * 32 + l4 * 8) * 2, 128));
        acc = __builtin_amdgcn_mfma_f32_16x16x32_bf16(pa[kt], vb, acc, 0, 0, 0);
      }
      ov[nt] = acc;
    }
#pragma unroll
    for (int nt = 0; nt < 4; ++nt) {
      int d = nt * 16 + l15;
      if (d < HDIM) {
        const float* lw = lepe_w + (h * HDIM + d) * 9;
        float w9[9];
#pragma unroll
        for (int t9 = 0; t9 < 9; ++t9) w9[t9] = lw[t9];
        float lb = lepe_b[h * HDIM + d];
#pragma unroll
        for (int r = 0; r < 4; ++r) {
          int m = wv * 16 + l4 * 4 + r;
          if (m < NTOK) {
            int y = m / 7, x0 = m - y * 7;
            float lac = lb;
#pragma unroll
            for (int dy = 0; dy < 3; ++dy)
#pragma unroll
              for (int dx = 0; dx < 3; ++dx) {
                int yy = y + dy - 1, xx = x0 + dx - 1;
                if (yy >= 0 && yy < 7 && xx >= 0 && xx < 7) {
                  float vvv = __bfloat162float(
                      *(const __hip_bfloat16*)(sm + swzaddr(VT_OFF, d, (yy * 7 + xx) * 2, 128)));
                  lac += w9[dy * 3 + dx] * vvv;
                }
              }
            *(__hip_bfloat16*)(sm + swzaddr(QS_OFF, m, d * 2, 128)) =
                __float2bfloat16(ov[nt][r] + lac);
          }
        }
      }
    }
    bf16x8 oa[2];
#pragma unroll
    for (int kt = 0; kt < 2; ++kt)
      oa[kt] = *(const bf16x8*)(sm + swzaddr(QS_OFF, arow, (kt * 32 + l4 * 8) * 2, 128));
#pragma unroll
    for (int nt = 0; nt < 12; ++nt) {
#pragma unroll
      for (int kt = 0; kt < 2; ++kt) {
        bf16x8 pb = *(const bf16x8*)(projwt + (nt * 16 + l15) * 384 + h * HDIM + kt * 32 + l4 * 8);
        pacc[nt] = __builtin_amdgcn_mfma_f32_16x16x32_bf16(oa[kt], pb, pacc[nt], 0, 0, 0);
      }
    }
    __syncthreads();
  }
  float* og = out + (size_t)blk * (NTOK * DIMC);
#pragma unroll
  for (int nt = 0; nt < 12; ++nt) {
#pragma unroll
    for (int r = 0; r < 4; ++r) {
      int m = wv * 16 + l4 * 4 + r;
      if (m < NTOK) og[m * DIMC + nt * 16 + l15] = pacc[nt][r];
    }
  }
}

// ==================== launcher ====================

extern "C" void kernel_launch(void* const* d_in, const int* in_sizes, int n_in,
                              void* d_out, int out_size, void* d_ws, size_t ws_size,
                              hipStream_t stream) {
  const float* x      = (const float*)d_in[0];
  const float* mask   = (const float*)d_in[1];
  const float* qkv_w  = (const float*)d_in[2];
  const float* qkv_b  = (const float*)d_in[3];
  const float* tbl    = (const float*)d_in[4];
  const int*   ridx   = (const int*)d_in[5];
  const float* lepe_w = (const float*)d_in[6];
  const float* lepe_b = (const float*)d_in[7];
  const float* proj_w = (const float*)d_in[8];
  const float* proj_b = (const float*)d_in[9];
  unsigned char* ws = (unsigned char*)d_ws;
  float* out = (float*)d_out;

  if (ws_size >= WS_NEED) {
    const int n_prep = 1008 * 192 + 192 * 352 + 1008 + 64 * 6 * 64 * 64 + 9 * 336;
    prep_main<<<dim3((n_prep + 255) / 256), dim3(256), 0, stream>>>(
        qkv_w, qkv_b, proj_w, tbl, ridx, mask, lepe_w, ws);
    qkv_gemm<<<dim3(7, 784), dim3(256), 0, stream>>>(x, ws);
    attn_head<<<dim3(6, 2048), dim3(256), 0, stream>>>(lepe_b, ws);
    proj_gemm<<<dim3(3, 784), dim3(256), 0, stream>>>(proj_b, ws, out);
  } else {
    prep_fb<<<dim3(1101), dim3(256), 0, stream>>>(qkv_w, proj_w, tbl, ridx, ws);
    winattn_fb<<<dim3(2048), dim3(256), 0, stream>>>(x, mask, qkv_b, lepe_w, lepe_b,
                                                     proj_b, ws, out);
  }
}